// Round 1
// baseline (1092.614 us; speedup 1.0000x reference)
//
#include <hip/hip_runtime.h>

// Rotated NMS, N boxes [xc,yc,w,h,theta_deg], scores. Output: first 1000 kept
// original indices in score-sorted order, -1 padded. All IoU math replicates
// the reference's float32 op order (contract off) to keep >0.7 decisions
// bit-consistent.

__global__ void rank_kernel(const float* __restrict__ scores,
                            int* __restrict__ order, int N) {
  int i = blockIdx.x * blockDim.x + threadIdx.x;
  if (i >= N) return;
  float si = scores[i];
  int r = 0;
  for (int j = 0; j < N; ++j) {
    float sj = scores[j];
    if (sj > si || (sj == si && j < i)) ++r;
  }
  order[r] = i;  // stable argsort(-scores)
}

__global__ void prep_kernel(const float* __restrict__ boxes,
                            const int* __restrict__ order,
                            float* __restrict__ sbox, int N) {
#pragma clang fp contract(off)
  int i = blockIdx.x * blockDim.x + threadIdx.x;
  if (i >= N) return;
  int b = order[i];
  float xc = boxes[b * 5 + 0], yc = boxes[b * 5 + 1];
  float w = boxes[b * 5 + 2], h = boxes[b * 5 + 3], th = boxes[b * 5 + 4];
  float ang = th * 0.017453292519943295f;  // deg2rad, float32-rounded
  float c = cosf(ang), s = sinf(ang);
  float dx = w * 0.5f, dy = h * 0.5f;
  const float lx[4] = {-dx, dx, dx, -dx};
  const float ly[4] = {-dy, -dy, dy, dy};
  float* o = sbox + (size_t)i * 12;
  for (int k = 0; k < 4; ++k) {
    // match reference: xc + lx*c - ly*s (no FMA)
    o[2 * k] = xc + lx[k] * c - ly[k] * s;
    o[2 * k + 1] = yc + lx[k] * s + ly[k] * c;
  }
  o[8] = xc;
  o[9] = yc;
  o[10] = 0.5f * sqrtf(w * w + h * h);  // bounding-circle radius
  o[11] = w * h;                        // area
}

__global__ void iou_kernel(const float* __restrict__ sbox,
                           unsigned long long* __restrict__ mask, int N,
                           int words) {
#pragma clang fp contract(off)
  int j = blockIdx.x * blockDim.x + threadIdx.x;
  int i = blockIdx.y;
  if (j >= N || j <= i) return;
  const float* A = sbox + (size_t)i * 12;  // subject (sorted row)
  const float* B = sbox + (size_t)j * 12;  // clipper (sorted col)
  // bounding-circle reject: disjoint circles => IoU == 0 => never > 0.7
  float ddx = B[8] - A[8], ddy = B[9] - A[9];
  float rs = A[10] + B[10];
  if (ddx * ddx + ddy * ddy > rs * rs) return;

  float Px[8], Py[8], Qx[8], Qy[8];
  for (int k = 0; k < 4; ++k) {
    Px[k] = A[2 * k];
    Py[k] = A[2 * k + 1];
  }
  int cnt = 4;
  // Sutherland-Hodgman: clip subject A by CCW edges of B.
  for (int e = 0; e < 4; ++e) {
    float ax = B[2 * e], ay = B[2 * e + 1];
    int e2 = (e + 1) & 3;
    float bx = B[2 * e2], by = B[2 * e2 + 1];
    float ex = bx - ax, ey = by - ay;
    int ncnt = 0;
    for (int k = 0; k < cnt; ++k) {
      int kn = (k + 1 < cnt) ? k + 1 : 0;
      // cross(a,b,p) = (b.x-a.x)*(p.y-a.y) - (b.y-a.y)*(p.x-a.x)
      float dc = ex * (Py[k] - ay) - ey * (Px[k] - ax);
      float dn = ex * (Py[kn] - ay) - ey * (Px[kn] - ax);
      bool ic = (dc >= 0.0f), inx = (dn >= 0.0f);
      if (ic) {
        if (ncnt < 8) {
          Qx[ncnt] = Px[k];
          Qy[ncnt] = Py[k];
        }
        ++ncnt;
      }
      if (ic != inx) {
        float denom = dc - dn;
        float t = (fabsf(denom) > 1e-12f) ? (dc / denom) : 0.0f;
        if (ncnt < 8) {
          Qx[ncnt] = Px[k] + t * (Px[kn] - Px[k]);
          Qy[ncnt] = Py[k] + t * (Py[kn] - Py[k]);
        }
        ++ncnt;
      }
    }
    cnt = ncnt > 8 ? 8 : ncnt;
    for (int k = 0; k < cnt; ++k) {
      Px[k] = Qx[k];
      Py[k] = Qy[k];
    }
  }
  float area = 0.0f;
  for (int k = 0; k < cnt; ++k) {
    int kn = (k + 1 < cnt) ? k + 1 : 0;
    area += Px[k] * Py[kn] - Px[kn] * Py[k];
  }
  float inter = fmaxf(0.5f * area, 0.0f);
  float uni = A[11] + B[11] - inter;
  float iou = inter / fmaxf(uni, 1e-9f);
  if (iou > 0.7f) {
    atomicOr(&mask[(size_t)i * words + (j >> 6)], 1ull << (j & 63));
  }
}

__global__ void nms_kernel(const unsigned long long* __restrict__ mask,
                           const int* __restrict__ order, int* __restrict__ out,
                           int N, int words, int topn) {
  __shared__ unsigned long long sup[64];
  int t = threadIdx.x;
  if (t < words) sup[t] = 0ull;
  __syncthreads();
  for (int i = 0; i < N; ++i) {
    bool is_sup = (sup[i >> 6] >> (i & 63)) & 1ull;
    __syncthreads();
    if (!is_sup && t < words) sup[t] |= mask[(size_t)i * words + t];
    __syncthreads();
  }
  if (t == 0) {
    int cnt = 0;
    for (int i = 0; i < N && cnt < topn; ++i) {
      if (!((sup[i >> 6] >> (i & 63)) & 1ull)) out[cnt++] = order[i];
    }
    for (int k = cnt; k < topn; ++k) out[k] = -1;
  }
}

extern "C" void kernel_launch(void* const* d_in, const int* in_sizes, int n_in,
                              void* d_out, int out_size, void* d_ws,
                              size_t ws_size, hipStream_t stream) {
  const float* boxes = (const float*)d_in[0];
  const float* scores = (const float*)d_in[1];
  int N = in_sizes[1];
  int words = (N + 63) / 64;

  char* ws = (char*)d_ws;
  unsigned long long* mask = (unsigned long long*)ws;
  size_t mask_bytes = (size_t)N * words * sizeof(unsigned long long);
  float* sbox = (float*)(ws + mask_bytes);
  size_t sbox_bytes = (size_t)N * 12 * sizeof(float);
  int* order = (int*)(ws + mask_bytes + sbox_bytes);
  int* out = (int*)d_out;

  hipMemsetAsync(mask, 0, mask_bytes, stream);
  int nb = (N + 255) / 256;
  rank_kernel<<<nb, 256, 0, stream>>>(scores, order, N);
  prep_kernel<<<nb, 256, 0, stream>>>(boxes, order, sbox, N);
  dim3 grid(nb, N);
  iou_kernel<<<grid, 256, 0, stream>>>(sbox, mask, N, words);
  nms_kernel<<<1, 64, 0, stream>>>(mask, order, out, N, words, out_size);
}

// Round 2
// 656.763 us; speedup vs baseline: 1.6636x; 1.6636x over previous
//
#include <hip/hip_runtime.h>

// Rotated NMS, N boxes [xc,yc,w,h,theta_deg], scores. Output: first 1000 kept
// original indices in score-sorted order, -1 padded. IoU math replicates the
// reference's float32 op order (contract off) to keep >0.7 decisions
// bit-consistent (round-1: absmax 0).

__global__ void rank_kernel(const float* __restrict__ scores,
                            int* __restrict__ order, int N) {
  __shared__ float s[4096];
  int staged = N < 4096 ? N : 4096;
  for (int k = threadIdx.x; k < staged; k += blockDim.x) s[k] = scores[k];
  __syncthreads();
  int i = blockIdx.x * blockDim.x + threadIdx.x;
  if (i >= N) return;
  float si = scores[i];
  int r = 0;
  for (int j = 0; j < N; ++j) {
    float sj = (j < staged) ? s[j] : scores[j];
    if (sj > si || (sj == si && j < i)) ++r;
  }
  order[r] = i;  // stable argsort(-scores)
}

__global__ void prep_kernel(const float* __restrict__ boxes,
                            const int* __restrict__ order,
                            float* __restrict__ sbox, int N) {
#pragma clang fp contract(off)
  int i = blockIdx.x * blockDim.x + threadIdx.x;
  if (i >= N) return;
  int b = order[i];
  float xc = boxes[b * 5 + 0], yc = boxes[b * 5 + 1];
  float w = boxes[b * 5 + 2], h = boxes[b * 5 + 3], th = boxes[b * 5 + 4];
  float ang = th * 0.017453292519943295f;
  float c = cosf(ang), s = sinf(ang);
  float dx = w * 0.5f, dy = h * 0.5f;
  const float lx[4] = {-dx, dx, dx, -dx};
  const float ly[4] = {-dy, -dy, dy, dy};
  float* o = sbox + (size_t)i * 12;
  for (int k = 0; k < 4; ++k) {
    o[2 * k] = xc + lx[k] * c - ly[k] * s;  // no FMA: match reference
    o[2 * k + 1] = yc + lx[k] * s + ly[k] * c;
  }
  o[8] = xc;
  o[9] = yc;
  o[10] = 0.5f * sqrtf(w * w + h * h);  // bounding-circle radius
  o[11] = w * h;                        // area
}

// Exact Sutherland-Hodgman clip of A by CCW edges of B; reference op order.
__device__ __forceinline__ float clip_inter_area(const float* __restrict__ A,
                                                 const float* __restrict__ B) {
#pragma clang fp contract(off)
  float Px[8], Py[8], Qx[8], Qy[8];
  for (int k = 0; k < 4; ++k) {
    Px[k] = A[2 * k];
    Py[k] = A[2 * k + 1];
  }
  int cnt = 4;
  for (int e = 0; e < 4; ++e) {
    float ax = B[2 * e], ay = B[2 * e + 1];
    int e2 = (e + 1) & 3;
    float bx = B[2 * e2], by = B[2 * e2 + 1];
    float ex = bx - ax, ey = by - ay;
    int ncnt = 0;
    for (int k = 0; k < cnt; ++k) {
      int kn = (k + 1 < cnt) ? k + 1 : 0;
      float dc = ex * (Py[k] - ay) - ey * (Px[k] - ax);
      float dn = ex * (Py[kn] - ay) - ey * (Px[kn] - ax);
      bool ic = (dc >= 0.0f), inx = (dn >= 0.0f);
      if (ic) {
        if (ncnt < 8) {
          Qx[ncnt] = Px[k];
          Qy[ncnt] = Py[k];
        }
        ++ncnt;
      }
      if (ic != inx) {
        float denom = dc - dn;
        float t = (fabsf(denom) > 1e-12f) ? (dc / denom) : 0.0f;
        if (ncnt < 8) {
          Qx[ncnt] = Px[k] + t * (Px[kn] - Px[k]);
          Qy[ncnt] = Py[k] + t * (Py[kn] - Py[k]);
        }
        ++ncnt;
      }
    }
    cnt = ncnt > 8 ? 8 : ncnt;
    for (int k = 0; k < cnt; ++k) {
      Px[k] = Qx[k];
      Py[k] = Qy[k];
    }
  }
  float area = 0.0f;
  for (int k = 0; k < cnt; ++k) {
    int kn = (k + 1 < cnt) ? k + 1 : 0;
    area += Px[k] * Py[kn] - Px[kn] * Py[k];
  }
  return fmaxf(0.5f * area, 0.0f);
}

__device__ __forceinline__ void emit_if_suppressed(
    const float* __restrict__ A, const float* __restrict__ B, int i, int j,
    unsigned long long* __restrict__ mask, int words) {
#pragma clang fp contract(off)
  float inter = clip_inter_area(A, B);
  float uni = A[11] + B[11] - inter;
  float iou = inter / fmaxf(uni, 1e-9f);
  if (iou > 0.7f)
    atomicOr(&mask[(size_t)i * words + (j >> 6)], 1ull << (j & 63));
}

// Phase A: conservative bounding-circle test; append survivor pairs.
__global__ void circle_kernel(const float* __restrict__ sbox,
                              unsigned int* __restrict__ pairs,
                              int* __restrict__ count, int N, int cap) {
  int j = blockIdx.x * blockDim.x + threadIdx.x;
  int i = blockIdx.y;
  bool keep = false;
  if (j < N && j > i) {
    const float* A = sbox + (size_t)i * 12;
    const float* B = sbox + (size_t)j * 12;
    float ddx = B[8] - A[8], ddy = B[9] - A[9];
    float rs = A[10] + B[10];
    keep = (ddx * ddx + ddy * ddy <= rs * rs);
  }
  unsigned long long ball = __ballot(keep);
  int lane = threadIdx.x & 63;
  int base = 0;
  if (lane == 0) {
    int nk = __popcll(ball);
    if (nk) base = atomicAdd(count, nk);
  }
  base = __shfl(base, 0);
  if (keep) {
    int off = __popcll(ball & ((1ull << lane) - 1ull));
    int dst = base + off;
    if (dst < cap) pairs[dst] = ((unsigned)i << 16) | (unsigned)j;
  }
}

// Phase B: dense clip over survivor list.
__global__ void clip_kernel(const float* __restrict__ sbox,
                            const unsigned int* __restrict__ pairs,
                            const int* __restrict__ count,
                            unsigned long long* __restrict__ mask, int words,
                            int cap) {
  int p = blockIdx.x * blockDim.x + threadIdx.x;
  int n = *count;
  if (n > cap) n = cap;
  if (p >= n) return;
  unsigned int pk = pairs[p];
  int i = pk >> 16, j = pk & 0xFFFF;
  const float* A = sbox + (size_t)i * 12;
  const float* B = sbox + (size_t)j * 12;
  emit_if_suppressed(A, B, i, j, mask, words);
}

// Fallback (small workspace): direct full-grid clip with circle reject.
__global__ void iou_direct_kernel(const float* __restrict__ sbox,
                                  unsigned long long* __restrict__ mask, int N,
                                  int words) {
  int j = blockIdx.x * blockDim.x + threadIdx.x;
  int i = blockIdx.y;
  if (j >= N || j <= i) return;
  const float* A = sbox + (size_t)i * 12;
  const float* B = sbox + (size_t)j * 12;
  float ddx = B[8] - A[8], ddy = B[9] - A[9];
  float rs = A[10] + B[10];
  if (ddx * ddx + ddy * ddy > rs * rs) return;
  emit_if_suppressed(A, B, i, j, mask, words);
}

// Greedy sweep: 64-row groups. Intra-group = 64 shfl|or steps on wave 0
// (mask bits only point forward, so supmask |= shfl(diag,l') is exact).
// Cross-group = parallel OR of kept rows into LDS suppression vector.
__global__ void __launch_bounds__(1024) nms_sweep(
    const unsigned long long* __restrict__ mask,
    const int* __restrict__ order, int* __restrict__ out, int N, int words,
    int topn) {
  __shared__ unsigned long long sup[64];
  __shared__ int prefix[65];
  int t = threadIdx.x;
  int lane = t & 63;
  int wave = t >> 6;
  if (t < words) sup[t] = 0ull;
  __syncthreads();

  int rstride = 1024 / words;  // rows per phase-2 pass
  int w2 = t % words;
  int rl0 = t / words;

  for (int g = 0; g < words; ++g) {
    if (wave == 0) {
      int r = g * 64 + lane;
      unsigned long long d =
          (r < N) ? mask[(size_t)r * words + g] : 0ull;
      unsigned long long supmask = sup[g];
      for (int lp = 0; lp < 64; ++lp) {
        if (!((supmask >> lp) & 1ull)) supmask |= __shfl(d, lp);
      }
      if (lane == 0) sup[g] = supmask;
    }
    __syncthreads();
    unsigned long long supg = sup[g];
    if (w2 > g) {
      unsigned long long acc = 0ull;
      for (int rl = rl0; rl < 64; rl += rstride) {
        if (!((supg >> rl) & 1ull)) {
          int r = g * 64 + rl;
          if (r < N) acc |= mask[(size_t)r * words + w2];
        }
      }
      if (acc) atomicOr(&sup[w2], acc);
    }
    __syncthreads();
  }

  // Output: per-word kept-count prefix, then parallel scatter.
  if (t == 0) {
    int acc = 0;
    for (int w = 0; w < words; ++w) {
      prefix[w] = acc;
      int hi = N - w * 64;
      unsigned long long keptw = ~sup[w];
      if (hi < 64) keptw &= (1ull << hi) - 1ull;
      acc += __popcll(keptw);
    }
    prefix[words] = acc;
  }
  __syncthreads();
  int total = prefix[words];
  for (int i = t; i < N; i += 1024) {
    int w = i >> 6, b = i & 63;
    if (!((sup[w] >> b) & 1ull)) {
      int pos = prefix[w] + __popcll(~sup[w] & ((1ull << b) - 1ull));
      if (pos < topn) out[pos] = order[i];
    }
  }
  for (int k = total + t; k < topn; k += 1024) out[k] = -1;
}

extern "C" void kernel_launch(void* const* d_in, const int* in_sizes, int n_in,
                              void* d_out, int out_size, void* d_ws,
                              size_t ws_size, hipStream_t stream) {
  const float* boxes = (const float*)d_in[0];
  const float* scores = (const float*)d_in[1];
  int N = in_sizes[1];
  int words = (N + 63) / 64;

  char* ws = (char*)d_ws;
  size_t off = 0;
  unsigned long long* mask = (unsigned long long*)(ws + off);
  size_t mask_bytes = (size_t)N * words * sizeof(unsigned long long);
  off += mask_bytes;
  float* sbox = (float*)(ws + off);
  off += (size_t)N * 12 * sizeof(float);
  int* order = (int*)(ws + off);
  off += (size_t)N * sizeof(int);
  int* count = (int*)(ws + off);
  off += 16;
  unsigned int* pairs = (unsigned int*)(ws + off);
  size_t maxpairs = (size_t)N * (N - 1) / 2;
  bool compaction = (off + maxpairs * 4 <= ws_size);
  int cap = compaction ? (int)maxpairs : 0;

  int* out = (int*)d_out;

  hipMemsetAsync(mask, 0, mask_bytes, stream);
  int nb = (N + 255) / 256;
  rank_kernel<<<nb, 256, 0, stream>>>(scores, order, N);
  prep_kernel<<<nb, 256, 0, stream>>>(boxes, order, sbox, N);
  if (compaction) {
    hipMemsetAsync(count, 0, sizeof(int), stream);
    dim3 grid(nb, N);
    circle_kernel<<<grid, 256, 0, stream>>>(sbox, pairs, count, N, cap);
    int pb = (int)((maxpairs + 255) / 256);
    clip_kernel<<<pb, 256, 0, stream>>>(sbox, pairs, count, mask, words, cap);
  } else {
    dim3 grid(nb, N);
    iou_direct_kernel<<<grid, 256, 0, stream>>>(sbox, mask, N, words);
  }
  nms_sweep<<<1, 1024, 0, stream>>>(mask, order, out, N, words, out_size);
}

// Round 3
// 362.251 us; speedup vs baseline: 3.0162x; 1.8130x over previous
//
#include <hip/hip_runtime.h>

// Rotated NMS, N boxes [xc,yc,w,h,theta_deg], scores. Output: first 1000 kept
// original indices in score-sorted order, -1 padded. IoU math replicates the
// reference's float32 op order (contract off) to keep >0.7 decisions
// bit-consistent (rounds 1-2: absmax 0).

__global__ void rank_kernel(const float* __restrict__ scores,
                            int* __restrict__ order, int N) {
  __shared__ float s[4096];
  int staged = N < 4096 ? N : 4096;
  for (int k = threadIdx.x; k < staged; k += blockDim.x) s[k] = scores[k];
  __syncthreads();
  int i = blockIdx.x * blockDim.x + threadIdx.x;
  if (i >= N) return;
  float si = scores[i];
  int r = 0;
  for (int j = 0; j < N; ++j) {
    float sj = (j < staged) ? s[j] : scores[j];
    if (sj > si || (sj == si && j < i)) ++r;
  }
  order[r] = i;  // stable argsort(-scores)
}

__global__ void prep_kernel(const float* __restrict__ boxes,
                            const int* __restrict__ order,
                            float* __restrict__ sbox, int N) {
#pragma clang fp contract(off)
  int i = blockIdx.x * blockDim.x + threadIdx.x;
  if (i >= N) return;
  int b = order[i];
  float xc = boxes[b * 5 + 0], yc = boxes[b * 5 + 1];
  float w = boxes[b * 5 + 2], h = boxes[b * 5 + 3], th = boxes[b * 5 + 4];
  float ang = th * 0.017453292519943295f;
  float c = cosf(ang), s = sinf(ang);
  float dx = w * 0.5f, dy = h * 0.5f;
  const float lx[4] = {-dx, dx, dx, -dx};
  const float ly[4] = {-dy, -dy, dy, dy};
  float* o = sbox + (size_t)i * 12;
  for (int k = 0; k < 4; ++k) {
    o[2 * k] = xc + lx[k] * c - ly[k] * s;  // no FMA: match reference
    o[2 * k + 1] = yc + lx[k] * s + ly[k] * c;
  }
  o[8] = xc;
  o[9] = yc;
  o[10] = 0.5f * sqrtf(w * w + h * h);  // bounding-circle radius
  o[11] = w * h;                        // area
}

// Exact Sutherland-Hodgman clip of A by CCW edges of B; reference op order.
__device__ __forceinline__ float clip_inter_area(const float* __restrict__ A,
                                                 const float* __restrict__ B) {
#pragma clang fp contract(off)
  float Px[8], Py[8], Qx[8], Qy[8];
  for (int k = 0; k < 4; ++k) {
    Px[k] = A[2 * k];
    Py[k] = A[2 * k + 1];
  }
  int cnt = 4;
  for (int e = 0; e < 4; ++e) {
    float ax = B[2 * e], ay = B[2 * e + 1];
    int e2 = (e + 1) & 3;
    float bx = B[2 * e2], by = B[2 * e2 + 1];
    float ex = bx - ax, ey = by - ay;
    int ncnt = 0;
    for (int k = 0; k < cnt; ++k) {
      int kn = (k + 1 < cnt) ? k + 1 : 0;
      float dc = ex * (Py[k] - ay) - ey * (Px[k] - ax);
      float dn = ex * (Py[kn] - ay) - ey * (Px[kn] - ax);
      bool ic = (dc >= 0.0f), inx = (dn >= 0.0f);
      if (ic) {
        if (ncnt < 8) {
          Qx[ncnt] = Px[k];
          Qy[ncnt] = Py[k];
        }
        ++ncnt;
      }
      if (ic != inx) {
        float denom = dc - dn;
        float t = (fabsf(denom) > 1e-12f) ? (dc / denom) : 0.0f;
        if (ncnt < 8) {
          Qx[ncnt] = Px[k] + t * (Px[kn] - Px[k]);
          Qy[ncnt] = Py[k] + t * (Py[kn] - Py[k]);
        }
        ++ncnt;
      }
    }
    cnt = ncnt > 8 ? 8 : ncnt;
    for (int k = 0; k < cnt; ++k) {
      Px[k] = Qx[k];
      Py[k] = Qy[k];
    }
  }
  float area = 0.0f;
  for (int k = 0; k < cnt; ++k) {
    int kn = (k + 1 < cnt) ? k + 1 : 0;
    area += Px[k] * Py[kn] - Px[kn] * Py[k];
  }
  return fmaxf(0.5f * area, 0.0f);
}

__device__ __forceinline__ void emit_if_suppressed(
    const float* __restrict__ A, const float* __restrict__ B, int i, int j,
    unsigned long long* __restrict__ mask, int words) {
#pragma clang fp contract(off)
  float inter = clip_inter_area(A, B);
  float uni = A[11] + B[11] - inter;
  float iou = inter / fmaxf(uni, 1e-9f);
  if (iou > 0.7f)
    atomicOr(&mask[(size_t)i * words + (j >> 6)], 1ull << (j & 63));
}

// Phase A: persistent blocks, LDS-staged centers, per-block survivor buffer,
// ONE global atomic per block (was one per wave -> 65536 same-address atomics
// = 312 us of serialization).
#define CC_BLOCKS 1024
#define CC_THREADS 256
__global__ void __launch_bounds__(CC_THREADS) circle_compact(
    const float* __restrict__ sbox, unsigned int* __restrict__ pairs,
    int* __restrict__ count, int N, int cap) {
  __shared__ float scx[2048], scy[2048], sr[2048];
  __shared__ unsigned int buf[4096];  // worst case: 16 iters * 256 all keep
  __shared__ int blk_cnt, blk_base;
  int t = threadIdx.x;
  if (t == 0) blk_cnt = 0;
  for (int k = t; k < N; k += CC_THREADS) {
    const float* o = sbox + (size_t)k * 12;
    scx[k] = o[8];
    scy[k] = o[9];
    sr[k] = o[10];
  }
  __syncthreads();
  long long total = (long long)N * N;
  for (long long p = (long long)blockIdx.x * CC_THREADS + t; p < total;
       p += (long long)gridDim.x * CC_THREADS) {
    int i = (int)(p / N);
    int j = (int)(p - (long long)i * N);
    if (j <= i) continue;
    float ddx = scx[j] - scx[i], ddy = scy[j] - scy[i];
    float rs = sr[i] + sr[j];
    if (ddx * ddx + ddy * ddy <= rs * rs) {
      int idx = atomicAdd(&blk_cnt, 1);  // LDS atomic: cheap
      buf[idx] = ((unsigned)i << 16) | (unsigned)j;
    }
  }
  __syncthreads();
  if (t == 0) blk_base = atomicAdd(count, blk_cnt);  // 1 global atomic/block
  __syncthreads();
  int n = blk_cnt, base = blk_base;
  for (int k = t; k < n; k += CC_THREADS)
    if (base + k < cap) pairs[base + k] = buf[k];
}

// Phase B: dense clip over survivor list, grid-stride.
__global__ void clip_kernel(const float* __restrict__ sbox,
                            const unsigned int* __restrict__ pairs,
                            const int* __restrict__ count,
                            unsigned long long* __restrict__ mask, int words,
                            int cap) {
  int n = *count;
  if (n > cap) n = cap;
  for (int p = blockIdx.x * blockDim.x + threadIdx.x; p < n;
       p += gridDim.x * blockDim.x) {
    unsigned int pk = pairs[p];
    int i = pk >> 16, j = pk & 0xFFFF;
    const float* A = sbox + (size_t)i * 12;
    const float* B = sbox + (size_t)j * 12;
    emit_if_suppressed(A, B, i, j, mask, words);
  }
}

// Fallback (small workspace or N>2048): direct grid with circle reject.
__global__ void iou_direct_kernel(const float* __restrict__ sbox,
                                  unsigned long long* __restrict__ mask, int N,
                                  int words) {
  int j = blockIdx.x * blockDim.x + threadIdx.x;
  int i = blockIdx.y;
  if (j >= N || j <= i) return;
  const float* A = sbox + (size_t)i * 12;
  const float* B = sbox + (size_t)j * 12;
  float ddx = B[8] - A[8], ddy = B[9] - A[9];
  float rs = A[10] + B[10];
  if (ddx * ddx + ddy * ddy > rs * rs) return;
  emit_if_suppressed(A, B, i, j, mask, words);
}

// Greedy sweep: 64-row groups. Intra-group = 64 shfl|or steps on wave 0
// (mask bits only point forward). Cross-group = parallel OR of kept rows.
__global__ void __launch_bounds__(1024) nms_sweep(
    const unsigned long long* __restrict__ mask,
    const int* __restrict__ order, int* __restrict__ out, int N, int words,
    int topn) {
  __shared__ unsigned long long sup[64];
  __shared__ int prefix[65];
  int t = threadIdx.x;
  int lane = t & 63;
  int wave = t >> 6;
  if (t < words) sup[t] = 0ull;
  __syncthreads();

  int rstride = 1024 / words;
  int w2 = t % words;
  int rl0 = t / words;

  for (int g = 0; g < words; ++g) {
    if (wave == 0) {
      int r = g * 64 + lane;
      unsigned long long d = (r < N) ? mask[(size_t)r * words + g] : 0ull;
      unsigned long long supmask = sup[g];
      for (int lp = 0; lp < 64; ++lp) {
        if (!((supmask >> lp) & 1ull)) supmask |= __shfl(d, lp);
      }
      if (lane == 0) sup[g] = supmask;
    }
    __syncthreads();
    unsigned long long supg = sup[g];
    if (w2 > g) {
      unsigned long long acc = 0ull;
      for (int rl = rl0; rl < 64; rl += rstride) {
        if (!((supg >> rl) & 1ull)) {
          int r = g * 64 + rl;
          if (r < N) acc |= mask[(size_t)r * words + w2];
        }
      }
      if (acc) atomicOr(&sup[w2], acc);
    }
    __syncthreads();
  }

  if (t == 0) {
    int acc = 0;
    for (int w = 0; w < words; ++w) {
      prefix[w] = acc;
      int hi = N - w * 64;
      unsigned long long keptw = ~sup[w];
      if (hi < 64) keptw &= (1ull << hi) - 1ull;
      acc += __popcll(keptw);
    }
    prefix[words] = acc;
  }
  __syncthreads();
  int total = prefix[words];
  for (int i = t; i < N; i += 1024) {
    int w = i >> 6, b = i & 63;
    if (!((sup[w] >> b) & 1ull)) {
      int pos = prefix[w] + __popcll(~sup[w] & ((1ull << b) - 1ull));
      if (pos < topn) out[pos] = order[i];
    }
  }
  for (int k = total + t; k < topn; k += 1024) out[k] = -1;
}

extern "C" void kernel_launch(void* const* d_in, const int* in_sizes, int n_in,
                              void* d_out, int out_size, void* d_ws,
                              size_t ws_size, hipStream_t stream) {
  const float* boxes = (const float*)d_in[0];
  const float* scores = (const float*)d_in[1];
  int N = in_sizes[1];
  int words = (N + 63) / 64;

  char* ws = (char*)d_ws;
  size_t off = 0;
  unsigned long long* mask = (unsigned long long*)(ws + off);
  size_t mask_bytes = (size_t)N * words * sizeof(unsigned long long);
  off += mask_bytes;
  float* sbox = (float*)(ws + off);
  off += (size_t)N * 12 * sizeof(float);
  int* order = (int*)(ws + off);
  off += (size_t)N * sizeof(int);
  int* count = (int*)(ws + off);
  off += 16;
  unsigned int* pairs = (unsigned int*)(ws + off);
  size_t maxpairs = (size_t)N * (N - 1) / 2;
  bool compaction = (N <= 2048) && (off + maxpairs * 4 <= ws_size);
  int cap = compaction ? (int)maxpairs : 0;

  int* out = (int*)d_out;

  hipMemsetAsync(mask, 0, mask_bytes, stream);
  int nb = (N + 255) / 256;
  rank_kernel<<<nb, 256, 0, stream>>>(scores, order, N);
  prep_kernel<<<nb, 256, 0, stream>>>(boxes, order, sbox, N);
  if (compaction) {
    hipMemsetAsync(count, 0, sizeof(int), stream);
    circle_compact<<<CC_BLOCKS, CC_THREADS, 0, stream>>>(sbox, pairs, count, N,
                                                         cap);
    clip_kernel<<<1024, 256, 0, stream>>>(sbox, pairs, count, mask, words, cap);
  } else {
    dim3 grid(nb, N);
    iou_direct_kernel<<<grid, 256, 0, stream>>>(sbox, mask, N, words);
  }
  nms_sweep<<<1, 1024, 0, stream>>>(mask, order, out, N, words, out_size);
}

// Round 4
// 205.217 us; speedup vs baseline: 5.3242x; 1.7652x over previous
//
#include <hip/hip_runtime.h>

// Rotated NMS, N boxes [xc,yc,w,h,theta_deg], scores. Output: first 1000 kept
// original indices in score-sorted order, -1 padded. IoU math replicates the
// reference's float32 op order (contract off) — rounds 1-3: absmax 0.

#define WL_LDS_CAP 4096   // sparse-sweep worklist cap (falls back to dense)
#define WL_G_CAP 65536    // global worklist capacity

// K1: fused rank+prep. Thread i computes rank r of box i (stable argsort by
// -score) and writes corners/center/radius/area straight to sbox[r].
__global__ void rankprep_kernel(const float* __restrict__ boxes,
                                const float* __restrict__ scores,
                                int* __restrict__ order,
                                float* __restrict__ sbox,
                                int* __restrict__ count,
                                int* __restrict__ wl_count, int N) {
#pragma clang fp contract(off)
  __shared__ float s[4096];
  int staged = N < 4096 ? N : 4096;
  for (int k = threadIdx.x; k < staged; k += blockDim.x) s[k] = scores[k];
  __syncthreads();
  if (blockIdx.x == 0 && threadIdx.x == 0) {
    *count = 0;
    *wl_count = 0;
  }
  int i = blockIdx.x * blockDim.x + threadIdx.x;
  if (i >= N) return;
  float si = scores[i];
  int r = 0;
  for (int j = 0; j < N; ++j) {
    float sj = (j < staged) ? s[j] : scores[j];
    if (sj > si || (sj == si && j < i)) ++r;
  }
  order[r] = i;
  float xc = boxes[i * 5 + 0], yc = boxes[i * 5 + 1];
  float w = boxes[i * 5 + 2], h = boxes[i * 5 + 3], th = boxes[i * 5 + 4];
  float ang = th * 0.017453292519943295f;
  float c = cosf(ang), sn = sinf(ang);
  float dx = w * 0.5f, dy = h * 0.5f;
  const float lx[4] = {-dx, dx, dx, -dx};
  const float ly[4] = {-dy, -dy, dy, dy};
  float* o = sbox + (size_t)r * 12;
  for (int k = 0; k < 4; ++k) {
    o[2 * k] = xc + lx[k] * c - ly[k] * sn;  // no FMA: match reference
    o[2 * k + 1] = yc + lx[k] * sn + ly[k] * c;
  }
  o[8] = xc;
  o[9] = yc;
  o[10] = 0.5f * sqrtf(w * w + h * h);
  o[11] = w * h;
}

// Exact Sutherland-Hodgman clip of A by CCW edges of B; reference op order.
__device__ __forceinline__ float clip_inter_area(const float* __restrict__ A,
                                                 const float* __restrict__ B) {
#pragma clang fp contract(off)
  float Px[8], Py[8], Qx[8], Qy[8];
  for (int k = 0; k < 4; ++k) {
    Px[k] = A[2 * k];
    Py[k] = A[2 * k + 1];
  }
  int cnt = 4;
  for (int e = 0; e < 4; ++e) {
    float ax = B[2 * e], ay = B[2 * e + 1];
    int e2 = (e + 1) & 3;
    float bx = B[2 * e2], by = B[2 * e2 + 1];
    float ex = bx - ax, ey = by - ay;
    int ncnt = 0;
    for (int k = 0; k < cnt; ++k) {
      int kn = (k + 1 < cnt) ? k + 1 : 0;
      float dc = ex * (Py[k] - ay) - ey * (Px[k] - ax);
      float dn = ex * (Py[kn] - ay) - ey * (Px[kn] - ax);
      bool ic = (dc >= 0.0f), inx = (dn >= 0.0f);
      if (ic) {
        if (ncnt < 8) {
          Qx[ncnt] = Px[k];
          Qy[ncnt] = Py[k];
        }
        ++ncnt;
      }
      if (ic != inx) {
        float denom = dc - dn;
        float t = (fabsf(denom) > 1e-12f) ? (dc / denom) : 0.0f;
        if (ncnt < 8) {
          Qx[ncnt] = Px[k] + t * (Px[kn] - Px[k]);
          Qy[ncnt] = Py[k] + t * (Py[kn] - Py[k]);
        }
        ++ncnt;
      }
    }
    cnt = ncnt > 8 ? 8 : ncnt;
    for (int k = 0; k < cnt; ++k) {
      Px[k] = Qx[k];
      Py[k] = Qy[k];
    }
  }
  float area = 0.0f;
  for (int k = 0; k < cnt; ++k) {
    int kn = (k + 1 < cnt) ? k + 1 : 0;
    area += Px[k] * Py[kn] - Px[kn] * Py[k];
  }
  return fmaxf(0.5f * area, 0.0f);
}

// K2: circle prefilter. Block b owns rows {b, N-1-b} (balanced: ~N cols
// total, no 64-bit division). Also zeroes the mask (replaces memset
// dispatch). One global atomic per block.
#define CC_T 256
__global__ void __launch_bounds__(CC_T) circle_compact(
    const float* __restrict__ sbox, unsigned long long* __restrict__ mask,
    int words, unsigned int* __restrict__ pairs, int* __restrict__ count,
    int N, int cap) {
  __shared__ float scx[2048], scy[2048], sr[2048];
  __shared__ unsigned int buf[2048];
  __shared__ int blk_cnt, blk_base;
  int t = threadIdx.x;
  size_t mtot = (size_t)N * words;
  for (size_t idx = (size_t)blockIdx.x * CC_T + t; idx < mtot;
       idx += (size_t)gridDim.x * CC_T)
    mask[idx] = 0ull;
  if (t == 0) blk_cnt = 0;
  for (int k = t; k < N; k += CC_T) {
    const float* o = sbox + (size_t)k * 12;
    scx[k] = o[8];
    scy[k] = o[9];
    sr[k] = o[10];
  }
  __syncthreads();
  int r0 = blockIdx.x, r1 = N - 1 - (int)blockIdx.x;
  for (int q = 0; q < 2; ++q) {
    int i = q ? r1 : r0;
    if (q && r1 == r0) break;
    float cxi = scx[i], cyi = scy[i], ri = sr[i];
    for (int j = i + 1 + t; j < N; j += CC_T) {
      float ddx = scx[j] - cxi, ddy = scy[j] - cyi;
      float rs = ri + sr[j];
      if (ddx * ddx + ddy * ddy <= rs * rs) {
        int idx = atomicAdd(&blk_cnt, 1);
        buf[idx] = ((unsigned)i << 16) | (unsigned)j;
      }
    }
  }
  __syncthreads();
  if (t == 0) blk_base = atomicAdd(count, blk_cnt);
  __syncthreads();
  for (int k = t; k < blk_cnt; k += CC_T)
    if (blk_base + k < cap) pairs[blk_base + k] = buf[k];
}

// K3: dense clip over survivors. First setter of each mask word appends
// (row,word) to the sparse worklist (atomicOr returns old value -> dedup).
__global__ void clip_kernel(const float* __restrict__ sbox,
                            const unsigned int* __restrict__ pairs,
                            const int* __restrict__ count,
                            unsigned long long* __restrict__ mask, int words,
                            int cap, unsigned int* __restrict__ wl,
                            int* __restrict__ wl_count) {
#pragma clang fp contract(off)
  int n = *count;
  if (n > cap) n = cap;
  for (int p = blockIdx.x * blockDim.x + threadIdx.x; p < n;
       p += gridDim.x * blockDim.x) {
    unsigned int pk = pairs[p];
    int i = pk >> 16, j = pk & 0xFFFF;
    const float* A = sbox + (size_t)i * 12;
    const float* B = sbox + (size_t)j * 12;
    float inter = clip_inter_area(A, B);
    float uni = A[11] + B[11] - inter;
    float iou = inter / fmaxf(uni, 1e-9f);
    if (iou > 0.7f) {
      unsigned long long old =
          atomicOr(&mask[(size_t)i * words + (j >> 6)], 1ull << (j & 63));
      if (old == 0ull) {
        int x = atomicAdd(wl_count, 1);
        if (x < WL_G_CAP) wl[x] = ((unsigned)i << 6) | (unsigned)(j >> 6);
      }
    }
  }
}

// Fallback direct path (large N / tiny workspace).
__global__ void iou_direct_kernel(const float* __restrict__ sbox,
                                  unsigned long long* __restrict__ mask, int N,
                                  int words) {
#pragma clang fp contract(off)
  int j = blockIdx.x * blockDim.x + threadIdx.x;
  int i = blockIdx.y;
  if (j >= N || j <= i) return;
  const float* A = sbox + (size_t)i * 12;
  const float* B = sbox + (size_t)j * 12;
  float ddx = B[8] - A[8], ddy = B[9] - A[9];
  float rs = A[10] + B[10];
  if (ddx * ddx + ddy * ddy > rs * rs) return;
  float inter = clip_inter_area(A, B);
  float uni = A[11] + B[11] - inter;
  float iou = inter / fmaxf(uni, 1e-9f);
  if (iou > 0.7f)
    atomicOr(&mask[(size_t)i * words + (j >> 6)], 1ull << (j & 63));
}

// K4: greedy sweep. Sparse path: counting-sort worklist by row, then one
// wave with register-resident sup (lane w owns word w) runs the serial
// chain barrier-free (~15 cyc/entry). Dense round-3 path as fallback.
__global__ void __launch_bounds__(1024) nms_sweep(
    const unsigned long long* __restrict__ mask, const int* __restrict__ order,
    const unsigned int* __restrict__ wl, const int* __restrict__ wl_count,
    int* __restrict__ out, int N, int words, int topn) {
  __shared__ unsigned long long sup_sh[64];
  __shared__ int prefix[65];
  __shared__ int h[2048], h2[2048];
  __shared__ unsigned int keys[WL_LDS_CAP];
  int t = threadIdx.x;
  int n_wl = *wl_count;  // uniform
  bool sparse = (words <= 32) && (N <= 2048) && (n_wl <= WL_LDS_CAP);

  if (sparse) {
    if (t < 64) sup_sh[t] = 0ull;
    for (int k = t; k < N; k += 1024) h[k] = 0;
    __syncthreads();
    for (int e = t; e < n_wl; e += 1024) atomicAdd(&h[wl[e] >> 6], 1);
    __syncthreads();
    // inclusive scan over rows (Hillis-Steele, ping-pong)
    int* src = h;
    int* dst = h2;
    for (int d = 1; d < N; d <<= 1) {
      for (int k = t; k < N; k += 1024)
        dst[k] = src[k] + (k >= d ? src[k - d] : 0);
      __syncthreads();
      int* tmp = src;
      src = dst;
      dst = tmp;
    }
    for (int k = t; k < N; k += 1024) dst[k] = k ? src[k - 1] : 0;
    __syncthreads();
    for (int e = t; e < n_wl; e += 1024) {
      unsigned key = wl[e];
      int pos = atomicAdd(&dst[key >> 6], 1);
      keys[pos] = key;
    }
    __syncthreads();
    if (t < 64) {
      int lane = t;
      unsigned long long sup = 0ull;
      unsigned long long supg = 0ull;
      int cur_g = -1;
      int chunks = (n_wl + 63) >> 6;
      for (int c = 0; c < chunks; ++c) {
        int idx = (c << 6) + lane;
        unsigned key = (idx < n_wl) ? keys[idx] : 0u;
        unsigned long long val = 0ull;
        if (idx < n_wl) {
          int rr = key >> 6, ww = key & 63;
          val = mask[(size_t)rr * words + ww];
        }
        int lim = n_wl - (c << 6);
        if (lim > 64) lim = 64;
        for (int e = 0; e < lim; ++e) {
          unsigned k2 = __shfl(key, e);
          unsigned long long v2 = __shfl(val, e);
          int r = k2 >> 6, w = k2 & 63, g = r >> 6;
          if (g != cur_g) {
            supg = __shfl(sup, g);
            cur_g = g;
          }
          bool kept = !((supg >> (r & 63)) & 1ull);
          if (kept) {
            if (lane == w) sup |= v2;
            if (w == g) supg |= v2;
          }
        }
      }
      sup_sh[lane] = (lane < words) ? sup : 0ull;
    }
    __syncthreads();
  } else {
    // dense fallback (round-3 algorithm)
    int lane = t & 63;
    int wave = t >> 6;
    if (t < 64) sup_sh[t] = 0ull;
    __syncthreads();
    int rstride = 1024 / words;
    int w2 = t % words;
    int rl0 = t / words;
    for (int g = 0; g < words; ++g) {
      if (wave == 0) {
        int r = g * 64 + lane;
        unsigned long long d = (r < N) ? mask[(size_t)r * words + g] : 0ull;
        unsigned long long supmask = sup_sh[g];
        for (int lp = 0; lp < 64; ++lp) {
          if (!((supmask >> lp) & 1ull)) supmask |= __shfl(d, lp);
        }
        if (lane == 0) sup_sh[g] = supmask;
      }
      __syncthreads();
      unsigned long long supg = sup_sh[g];
      if (w2 > g) {
        unsigned long long acc = 0ull;
        for (int rl = rl0; rl < 64; rl += rstride) {
          if (!((supg >> rl) & 1ull)) {
            int r = g * 64 + rl;
            if (r < N) acc |= mask[(size_t)r * words + w2];
          }
        }
        if (acc) atomicOr(&sup_sh[w2], acc);
      }
      __syncthreads();
    }
  }

  // output: per-word kept prefix, parallel scatter, -1 pad
  if (t == 0) {
    int acc = 0;
    for (int w = 0; w < words; ++w) {
      prefix[w] = acc;
      int hi = N - w * 64;
      unsigned long long keptw = ~sup_sh[w];
      if (hi < 64) keptw &= (1ull << hi) - 1ull;
      acc += __popcll(keptw);
    }
    prefix[words] = acc;
  }
  __syncthreads();
  int total = prefix[words];
  for (int i = t; i < N; i += 1024) {
    int w = i >> 6, b = i & 63;
    if (!((sup_sh[w] >> b) & 1ull)) {
      int pos = prefix[w] + __popcll(~sup_sh[w] & ((1ull << b) - 1ull));
      if (pos < topn) out[pos] = order[i];
    }
  }
  for (int k = total + t; k < topn; k += 1024) out[k] = -1;
}

extern "C" void kernel_launch(void* const* d_in, const int* in_sizes, int n_in,
                              void* d_out, int out_size, void* d_ws,
                              size_t ws_size, hipStream_t stream) {
  const float* boxes = (const float*)d_in[0];
  const float* scores = (const float*)d_in[1];
  int N = in_sizes[1];
  int words = (N + 63) / 64;

  char* ws = (char*)d_ws;
  size_t off = 0;
  unsigned long long* mask = (unsigned long long*)(ws + off);
  off += (size_t)N * words * sizeof(unsigned long long);
  float* sbox = (float*)(ws + off);
  off += (size_t)N * 12 * sizeof(float);
  int* order = (int*)(ws + off);
  off += (size_t)N * sizeof(int);
  int* count = (int*)(ws + off);
  int* wl_count = count + 1;
  off += 16;
  unsigned int* wl = (unsigned int*)(ws + off);
  off += (size_t)WL_G_CAP * sizeof(unsigned int);
  unsigned int* pairs = (unsigned int*)(ws + off);
  size_t maxpairs = (size_t)N * (N - 1) / 2;
  bool compaction = (N <= 2048) && (off + maxpairs * 4 <= ws_size);
  int cap = compaction ? (int)maxpairs : 0;

  int* out = (int*)d_out;

  int nb = (N + 255) / 256;
  rankprep_kernel<<<nb, 256, 0, stream>>>(boxes, scores, order, sbox, count,
                                          wl_count, N);
  if (compaction) {
    circle_compact<<<(N + 1) / 2, CC_T, 0, stream>>>(sbox, mask, words, pairs,
                                                     count, N, cap);
    clip_kernel<<<256, 256, 0, stream>>>(sbox, pairs, count, mask, words, cap,
                                         wl, wl_count);
  } else {
    hipMemsetAsync(mask, 0, (size_t)N * words * 8, stream);
    dim3 grid(nb, N);
    iou_direct_kernel<<<grid, 256, 0, stream>>>(sbox, mask, N, words);
  }
  nms_sweep<<<1, 1024, 0, stream>>>(mask, order, wl, wl_count, out, N, words,
                                    out_size);
}

// Round 5
// 160.476 us; speedup vs baseline: 6.8086x; 1.2788x over previous
//
#include <hip/hip_runtime.h>

// Rotated NMS, N boxes [xc,yc,w,h,theta_deg], scores. Output: first 1000 kept
// original indices in score-sorted order, -1 padded. IoU math replicates the
// reference's float32 op order (contract off) — rounds 1-4: absmax 0.

#define WL_LDS_CAP 4096   // sparse-sweep worklist cap (falls back to dense)
#define WL_G_CAP 65536    // global worklist capacity

// K1: fused rank+prep. Thread i computes rank r of box i (stable argsort by
// -score) and writes corners/center/radius/area straight to sbox[r].
// Rank loop split LDS-body/global-tail + unroll4 x 4 accumulators so the
// broadcast ds_reads pipeline (round-4: single dependent ds_read chain
// = 112 us at 1 wave/SIMD).
__global__ void rankprep_kernel(const float* __restrict__ boxes,
                                const float* __restrict__ scores,
                                int* __restrict__ order,
                                float* __restrict__ sbox,
                                int* __restrict__ count,
                                int* __restrict__ wl_count, int N) {
#pragma clang fp contract(off)
  __shared__ float s[4096];
  int staged = N < 4096 ? N : 4096;
  for (int k = threadIdx.x; k < staged; k += blockDim.x) s[k] = scores[k];
  __syncthreads();
  if (blockIdx.x == 0 && threadIdx.x == 0) {
    *count = 0;
    *wl_count = 0;
  }
  int i = blockIdx.x * blockDim.x + threadIdx.x;
  if (i >= N) return;
  float si = scores[i];
  int r0 = 0, r1 = 0, r2 = 0, r3 = 0;
  int j = 0;
#pragma unroll 4
  for (; j + 4 <= staged; j += 4) {
    float a = s[j], b = s[j + 1], c = s[j + 2], d = s[j + 3];
    r0 += (a > si) || (a == si && (j + 0) < i);
    r1 += (b > si) || (b == si && (j + 1) < i);
    r2 += (c > si) || (c == si && (j + 2) < i);
    r3 += (d > si) || (d == si && (j + 3) < i);
  }
  for (; j < staged; ++j) {
    float a = s[j];
    r0 += (a > si) || (a == si && j < i);
  }
  for (; j < N; ++j) {  // global tail (N > 4096 only)
    float a = scores[j];
    r0 += (a > si) || (a == si && j < i);
  }
  int r = r0 + r1 + r2 + r3;
  order[r] = i;
  float xc = boxes[i * 5 + 0], yc = boxes[i * 5 + 1];
  float w = boxes[i * 5 + 2], h = boxes[i * 5 + 3], th = boxes[i * 5 + 4];
  float ang = th * 0.017453292519943295f;
  float c = cosf(ang), sn = sinf(ang);
  float dx = w * 0.5f, dy = h * 0.5f;
  const float lx[4] = {-dx, dx, dx, -dx};
  const float ly[4] = {-dy, -dy, dy, dy};
  float* o = sbox + (size_t)r * 12;
  for (int k = 0; k < 4; ++k) {
    o[2 * k] = xc + lx[k] * c - ly[k] * sn;  // no FMA: match reference
    o[2 * k + 1] = yc + lx[k] * sn + ly[k] * c;
  }
  o[8] = xc;
  o[9] = yc;
  o[10] = 0.5f * sqrtf(w * w + h * h);
  o[11] = w * h;
}

// Exact Sutherland-Hodgman clip of A by CCW edges of B; reference op order.
__device__ __forceinline__ float clip_inter_area(const float* __restrict__ A,
                                                 const float* __restrict__ B) {
#pragma clang fp contract(off)
  float Px[8], Py[8], Qx[8], Qy[8];
  for (int k = 0; k < 4; ++k) {
    Px[k] = A[2 * k];
    Py[k] = A[2 * k + 1];
  }
  int cnt = 4;
  for (int e = 0; e < 4; ++e) {
    float ax = B[2 * e], ay = B[2 * e + 1];
    int e2 = (e + 1) & 3;
    float bx = B[2 * e2], by = B[2 * e2 + 1];
    float ex = bx - ax, ey = by - ay;
    int ncnt = 0;
    for (int k = 0; k < cnt; ++k) {
      int kn = (k + 1 < cnt) ? k + 1 : 0;
      float dc = ex * (Py[k] - ay) - ey * (Px[k] - ax);
      float dn = ex * (Py[kn] - ay) - ey * (Px[kn] - ax);
      bool ic = (dc >= 0.0f), inx = (dn >= 0.0f);
      if (ic) {
        if (ncnt < 8) {
          Qx[ncnt] = Px[k];
          Qy[ncnt] = Py[k];
        }
        ++ncnt;
      }
      if (ic != inx) {
        float denom = dc - dn;
        float t = (fabsf(denom) > 1e-12f) ? (dc / denom) : 0.0f;
        if (ncnt < 8) {
          Qx[ncnt] = Px[k] + t * (Px[kn] - Px[k]);
          Qy[ncnt] = Py[k] + t * (Py[kn] - Py[k]);
        }
        ++ncnt;
      }
    }
    cnt = ncnt > 8 ? 8 : ncnt;
    for (int k = 0; k < cnt; ++k) {
      Px[k] = Qx[k];
      Py[k] = Qy[k];
    }
  }
  float area = 0.0f;
  for (int k = 0; k < cnt; ++k) {
    int kn = (k + 1 < cnt) ? k + 1 : 0;
    area += Px[k] * Py[kn] - Px[kn] * Py[k];
  }
  return fmaxf(0.5f * area, 0.0f);
}

// K2: circle prefilter. Block b owns rows {b, N-1-b} (balanced). Also zeroes
// the mask (replaces memset dispatch). One global atomic per block.
#define CC_T 256
__global__ void __launch_bounds__(CC_T) circle_compact(
    const float* __restrict__ sbox, unsigned long long* __restrict__ mask,
    int words, unsigned int* __restrict__ pairs, int* __restrict__ count,
    int N, int cap) {
  __shared__ float scx[2048], scy[2048], sr[2048];
  __shared__ unsigned int buf[2048];
  __shared__ int blk_cnt, blk_base;
  int t = threadIdx.x;
  size_t mtot = (size_t)N * words;
  for (size_t idx = (size_t)blockIdx.x * CC_T + t; idx < mtot;
       idx += (size_t)gridDim.x * CC_T)
    mask[idx] = 0ull;
  if (t == 0) blk_cnt = 0;
  for (int k = t; k < N; k += CC_T) {
    const float* o = sbox + (size_t)k * 12;
    scx[k] = o[8];
    scy[k] = o[9];
    sr[k] = o[10];
  }
  __syncthreads();
  int r0 = blockIdx.x, r1 = N - 1 - (int)blockIdx.x;
  for (int q = 0; q < 2; ++q) {
    int i = q ? r1 : r0;
    if (q && r1 == r0) break;
    float cxi = scx[i], cyi = scy[i], ri = sr[i];
    for (int j = i + 1 + t; j < N; j += CC_T) {
      float ddx = scx[j] - cxi, ddy = scy[j] - cyi;
      float rs = ri + sr[j];
      if (ddx * ddx + ddy * ddy <= rs * rs) {
        int idx = atomicAdd(&blk_cnt, 1);
        buf[idx] = ((unsigned)i << 16) | (unsigned)j;
      }
    }
  }
  __syncthreads();
  if (t == 0) blk_base = atomicAdd(count, blk_cnt);
  __syncthreads();
  for (int k = t; k < blk_cnt; k += CC_T)
    if (blk_base + k < cap) pairs[blk_base + k] = buf[k];
}

// K3: dense clip over survivors. First setter of each mask word appends
// (row,word) to the sparse worklist (atomicOr returns old value -> dedup).
__global__ void clip_kernel(const float* __restrict__ sbox,
                            const unsigned int* __restrict__ pairs,
                            const int* __restrict__ count,
                            unsigned long long* __restrict__ mask, int words,
                            int cap, unsigned int* __restrict__ wl,
                            int* __restrict__ wl_count) {
#pragma clang fp contract(off)
  int n = *count;
  if (n > cap) n = cap;
  for (int p = blockIdx.x * blockDim.x + threadIdx.x; p < n;
       p += gridDim.x * blockDim.x) {
    unsigned int pk = pairs[p];
    int i = pk >> 16, j = pk & 0xFFFF;
    const float* A = sbox + (size_t)i * 12;
    const float* B = sbox + (size_t)j * 12;
    float inter = clip_inter_area(A, B);
    float uni = A[11] + B[11] - inter;
    float iou = inter / fmaxf(uni, 1e-9f);
    if (iou > 0.7f) {
      unsigned long long old =
          atomicOr(&mask[(size_t)i * words + (j >> 6)], 1ull << (j & 63));
      if (old == 0ull) {
        int x = atomicAdd(wl_count, 1);
        if (x < WL_G_CAP) wl[x] = ((unsigned)i << 6) | (unsigned)(j >> 6);
      }
    }
  }
}

// Fallback direct path (large N / tiny workspace).
__global__ void iou_direct_kernel(const float* __restrict__ sbox,
                                  unsigned long long* __restrict__ mask, int N,
                                  int words) {
#pragma clang fp contract(off)
  int j = blockIdx.x * blockDim.x + threadIdx.x;
  int i = blockIdx.y;
  if (j >= N || j <= i) return;
  const float* A = sbox + (size_t)i * 12;
  const float* B = sbox + (size_t)j * 12;
  float ddx = B[8] - A[8], ddy = B[9] - A[9];
  float rs = A[10] + B[10];
  if (ddx * ddx + ddy * ddy > rs * rs) return;
  float inter = clip_inter_area(A, B);
  float uni = A[11] + B[11] - inter;
  float iou = inter / fmaxf(uni, 1e-9f);
  if (iou > 0.7f)
    atomicOr(&mask[(size_t)i * words + (j >> 6)], 1ull << (j & 63));
}

// K4: greedy sweep. Sparse path: counting-sort worklist by row, then one
// wave with register-resident sup (lane w owns word w) runs the serial
// chain barrier-free. Dense round-3 path as fallback.
__global__ void __launch_bounds__(1024) nms_sweep(
    const unsigned long long* __restrict__ mask, const int* __restrict__ order,
    const unsigned int* __restrict__ wl, const int* __restrict__ wl_count,
    int* __restrict__ out, int N, int words, int topn) {
  __shared__ unsigned long long sup_sh[64];
  __shared__ int prefix[65];
  __shared__ int h[2048], h2[2048];
  __shared__ unsigned int keys[WL_LDS_CAP];
  int t = threadIdx.x;
  int n_wl = *wl_count;  // uniform
  bool sparse = (words <= 32) && (N <= 2048) && (n_wl <= WL_LDS_CAP);

  if (sparse) {
    if (t < 64) sup_sh[t] = 0ull;
    for (int k = t; k < N; k += 1024) h[k] = 0;
    __syncthreads();
    for (int e = t; e < n_wl; e += 1024) atomicAdd(&h[wl[e] >> 6], 1);
    __syncthreads();
    // inclusive scan over rows (Hillis-Steele, ping-pong)
    int* src = h;
    int* dst = h2;
    for (int d = 1; d < N; d <<= 1) {
      for (int k = t; k < N; k += 1024)
        dst[k] = src[k] + (k >= d ? src[k - d] : 0);
      __syncthreads();
      int* tmp = src;
      src = dst;
      dst = tmp;
    }
    for (int k = t; k < N; k += 1024) dst[k] = k ? src[k - 1] : 0;
    __syncthreads();
    for (int e = t; e < n_wl; e += 1024) {
      unsigned key = wl[e];
      int pos = atomicAdd(&dst[key >> 6], 1);
      keys[pos] = key;
    }
    __syncthreads();
    if (t < 64) {
      int lane = t;
      unsigned long long sup = 0ull;
      unsigned long long supg = 0ull;
      int cur_g = -1;
      int chunks = (n_wl + 63) >> 6;
      for (int c = 0; c < chunks; ++c) {
        int idx = (c << 6) + lane;
        unsigned key = (idx < n_wl) ? keys[idx] : 0u;
        unsigned long long val = 0ull;
        if (idx < n_wl) {
          int rr = key >> 6, ww = key & 63;
          val = mask[(size_t)rr * words + ww];
        }
        int lim = n_wl - (c << 6);
        if (lim > 64) lim = 64;
        for (int e = 0; e < lim; ++e) {
          unsigned k2 = __shfl(key, e);
          unsigned long long v2 = __shfl(val, e);
          int r = k2 >> 6, w = k2 & 63, g = r >> 6;
          if (g != cur_g) {
            supg = __shfl(sup, g);
            cur_g = g;
          }
          bool kept = !((supg >> (r & 63)) & 1ull);
          if (kept) {
            if (lane == w) sup |= v2;
            if (w == g) supg |= v2;
          }
        }
      }
      sup_sh[lane] = (lane < words) ? sup : 0ull;
    }
    __syncthreads();
  } else {
    // dense fallback (round-3 algorithm)
    int lane = t & 63;
    int wave = t >> 6;
    if (t < 64) sup_sh[t] = 0ull;
    __syncthreads();
    int rstride = 1024 / words;
    int w2 = t % words;
    int rl0 = t / words;
    for (int g = 0; g < words; ++g) {
      if (wave == 0) {
        int r = g * 64 + lane;
        unsigned long long d = (r < N) ? mask[(size_t)r * words + g] : 0ull;
        unsigned long long supmask = sup_sh[g];
        for (int lp = 0; lp < 64; ++lp) {
          if (!((supmask >> lp) & 1ull)) supmask |= __shfl(d, lp);
        }
        if (lane == 0) sup_sh[g] = supmask;
      }
      __syncthreads();
      unsigned long long supg = sup_sh[g];
      if (w2 > g) {
        unsigned long long acc = 0ull;
        for (int rl = rl0; rl < 64; rl += rstride) {
          if (!((supg >> rl) & 1ull)) {
            int r = g * 64 + rl;
            if (r < N) acc |= mask[(size_t)r * words + w2];
          }
        }
        if (acc) atomicOr(&sup_sh[w2], acc);
      }
      __syncthreads();
    }
  }

  // output: per-word kept prefix, parallel scatter, -1 pad
  if (t == 0) {
    int acc = 0;
    for (int w = 0; w < words; ++w) {
      prefix[w] = acc;
      int hi = N - w * 64;
      unsigned long long keptw = ~sup_sh[w];
      if (hi < 64) keptw &= (1ull << hi) - 1ull;
      acc += __popcll(keptw);
    }
    prefix[words] = acc;
  }
  __syncthreads();
  int total = prefix[words];
  for (int i = t; i < N; i += 1024) {
    int w = i >> 6, b = i & 63;
    if (!((sup_sh[w] >> b) & 1ull)) {
      int pos = prefix[w] + __popcll(~sup_sh[w] & ((1ull << b) - 1ull));
      if (pos < topn) out[pos] = order[i];
    }
  }
  for (int k = total + t; k < topn; k += 1024) out[k] = -1;
}

extern "C" void kernel_launch(void* const* d_in, const int* in_sizes, int n_in,
                              void* d_out, int out_size, void* d_ws,
                              size_t ws_size, hipStream_t stream) {
  const float* boxes = (const float*)d_in[0];
  const float* scores = (const float*)d_in[1];
  int N = in_sizes[1];
  int words = (N + 63) / 64;

  char* ws = (char*)d_ws;
  size_t off = 0;
  unsigned long long* mask = (unsigned long long*)(ws + off);
  off += (size_t)N * words * sizeof(unsigned long long);
  float* sbox = (float*)(ws + off);
  off += (size_t)N * 12 * sizeof(float);
  int* order = (int*)(ws + off);
  off += (size_t)N * sizeof(int);
  int* count = (int*)(ws + off);
  int* wl_count = count + 1;
  off += 16;
  unsigned int* wl = (unsigned int*)(ws + off);
  off += (size_t)WL_G_CAP * sizeof(unsigned int);
  unsigned int* pairs = (unsigned int*)(ws + off);
  size_t maxpairs = (size_t)N * (N - 1) / 2;
  bool compaction = (N <= 2048) && (off + maxpairs * 4 <= ws_size);
  int cap = compaction ? (int)maxpairs : 0;

  int* out = (int*)d_out;

  int nb = (N + 255) / 256;
  rankprep_kernel<<<nb, 256, 0, stream>>>(boxes, scores, order, sbox, count,
                                          wl_count, N);
  if (compaction) {
    circle_compact<<<(N + 1) / 2, CC_T, 0, stream>>>(sbox, mask, words, pairs,
                                                     count, N, cap);
    clip_kernel<<<256, 256, 0, stream>>>(sbox, pairs, count, mask, words, cap,
                                         wl, wl_count);
  } else {
    hipMemsetAsync(mask, 0, (size_t)N * words * 8, stream);
    dim3 grid(nb, N);
    iou_direct_kernel<<<grid, 256, 0, stream>>>(sbox, mask, N, words);
  }
  nms_sweep<<<1, 1024, 0, stream>>>(mask, order, wl, wl_count, out, N, words,
                                    out_size);
}

// Round 6
// 105.919 us; speedup vs baseline: 10.3156x; 1.5151x over previous
//
#include <hip/hip_runtime.h>

// Rotated NMS, N boxes [xc,yc,w,h,theta_deg], scores. Output: first 1000 kept
// original indices in score-sorted order, -1 padded. IoU math replicates the
// reference's float32 op order (contract off) — rounds 1-5: absmax 0.

#define WL_LDS_CAP 4096   // sparse-sweep worklist cap (falls back to dense)
#define WL_G_CAP 65536    // global worklist capacity
#define RT 256            // rank tile size

// K1: tiled rank. Block (bi,bj): threads = i-tile bi, LDS = j-tile bj.
// rank_part[bj][i] = #{j in tile bj : s_j > s_i || (s_j==s_i && j<i)}.
// Round-5 lesson: single-tile version had 8 blocks on 8 CUs (occupancy
// 0.33%) and was pure LDS-latency serialization; 64 blocks x 1/8 work
// each = ~64x more throughput.
__global__ void rank_tiles(const float* __restrict__ scores,
                           int* __restrict__ rank_part,
                           int* __restrict__ count,
                           int* __restrict__ wl_count, int N) {
  __shared__ float4 s4[RT / 4];
  if (blockIdx.x == 0 && blockIdx.y == 0 && threadIdx.x == 0) {
    *count = 0;
    *wl_count = 0;
  }
  int t = threadIdx.x;
  int jbase = blockIdx.y * RT;
  if (t < RT / 4) {
    int j0 = jbase + t * 4;
    float4 v;
    const float nanf_ = __int_as_float(0x7fc00000);  // pad: all cmps false
    v.x = (j0 + 0 < N) ? scores[j0 + 0] : nanf_;
    v.y = (j0 + 1 < N) ? scores[j0 + 1] : nanf_;
    v.z = (j0 + 2 < N) ? scores[j0 + 2] : nanf_;
    v.w = (j0 + 3 < N) ? scores[j0 + 3] : nanf_;
    s4[t] = v;
  }
  __syncthreads();
  int i = blockIdx.x * RT + t;
  if (i >= N) return;
  float si = scores[i];
  int r0 = 0, r1 = 0, r2 = 0, r3 = 0;
#pragma unroll 4
  for (int q = 0; q < RT / 4; ++q) {
    float4 v = s4[q];
    int jb = jbase + q * 4;
    r0 += (v.x > si) || (v.x == si && (jb + 0) < i);
    r1 += (v.y > si) || (v.y == si && (jb + 1) < i);
    r2 += (v.z > si) || (v.z == si && (jb + 2) < i);
    r3 += (v.w > si) || (v.w == si && (jb + 3) < i);
  }
  rank_part[(size_t)blockIdx.y * N + i] = r0 + r1 + r2 + r3;
}

// K2: sum partials -> rank r; scatter order[r]=i and prep sbox[r].
__global__ void scatter_prep(const float* __restrict__ boxes,
                             const int* __restrict__ rank_part, int tiles,
                             int* __restrict__ order, float* __restrict__ sbox,
                             int N) {
#pragma clang fp contract(off)
  int i = blockIdx.x * blockDim.x + threadIdx.x;
  if (i >= N) return;
  int r = 0;
  for (int b = 0; b < tiles; ++b) r += rank_part[(size_t)b * N + i];
  order[r] = i;
  float xc = boxes[i * 5 + 0], yc = boxes[i * 5 + 1];
  float w = boxes[i * 5 + 2], h = boxes[i * 5 + 3], th = boxes[i * 5 + 4];
  float ang = th * 0.017453292519943295f;
  float c = cosf(ang), sn = sinf(ang);
  float dx = w * 0.5f, dy = h * 0.5f;
  const float lx[4] = {-dx, dx, dx, -dx};
  const float ly[4] = {-dy, -dy, dy, dy};
  float* o = sbox + (size_t)r * 12;
  for (int k = 0; k < 4; ++k) {
    o[2 * k] = xc + lx[k] * c - ly[k] * sn;  // no FMA: match reference
    o[2 * k + 1] = yc + lx[k] * sn + ly[k] * c;
  }
  o[8] = xc;
  o[9] = yc;
  o[10] = 0.5f * sqrtf(w * w + h * h);
  o[11] = w * h;
}

// Exact Sutherland-Hodgman clip of A by CCW edges of B; reference op order.
__device__ __forceinline__ float clip_inter_area(const float* __restrict__ A,
                                                 const float* __restrict__ B) {
#pragma clang fp contract(off)
  float Px[8], Py[8], Qx[8], Qy[8];
  for (int k = 0; k < 4; ++k) {
    Px[k] = A[2 * k];
    Py[k] = A[2 * k + 1];
  }
  int cnt = 4;
  for (int e = 0; e < 4; ++e) {
    float ax = B[2 * e], ay = B[2 * e + 1];
    int e2 = (e + 1) & 3;
    float bx = B[2 * e2], by = B[2 * e2 + 1];
    float ex = bx - ax, ey = by - ay;
    int ncnt = 0;
    for (int k = 0; k < cnt; ++k) {
      int kn = (k + 1 < cnt) ? k + 1 : 0;
      float dc = ex * (Py[k] - ay) - ey * (Px[k] - ax);
      float dn = ex * (Py[kn] - ay) - ey * (Px[kn] - ax);
      bool ic = (dc >= 0.0f), inx = (dn >= 0.0f);
      if (ic) {
        if (ncnt < 8) {
          Qx[ncnt] = Px[k];
          Qy[ncnt] = Py[k];
        }
        ++ncnt;
      }
      if (ic != inx) {
        float denom = dc - dn;
        float t = (fabsf(denom) > 1e-12f) ? (dc / denom) : 0.0f;
        if (ncnt < 8) {
          Qx[ncnt] = Px[k] + t * (Px[kn] - Px[k]);
          Qy[ncnt] = Py[k] + t * (Py[kn] - Py[k]);
        }
        ++ncnt;
      }
    }
    cnt = ncnt > 8 ? 8 : ncnt;
    for (int k = 0; k < cnt; ++k) {
      Px[k] = Qx[k];
      Py[k] = Qy[k];
    }
  }
  float area = 0.0f;
  for (int k = 0; k < cnt; ++k) {
    int kn = (k + 1 < cnt) ? k + 1 : 0;
    area += Px[k] * Py[kn] - Px[kn] * Py[k];
  }
  return fmaxf(0.5f * area, 0.0f);
}

// K3: circle prefilter. Block b owns rows {b, N-1-b} (balanced). Also zeroes
// the mask (replaces memset dispatch). One global atomic per block.
#define CC_T 256
__global__ void __launch_bounds__(CC_T) circle_compact(
    const float* __restrict__ sbox, unsigned long long* __restrict__ mask,
    int words, unsigned int* __restrict__ pairs, int* __restrict__ count,
    int N, int cap) {
  __shared__ float scx[2048], scy[2048], sr[2048];
  __shared__ unsigned int buf[2048];
  __shared__ int blk_cnt, blk_base;
  int t = threadIdx.x;
  size_t mtot = (size_t)N * words;
  for (size_t idx = (size_t)blockIdx.x * CC_T + t; idx < mtot;
       idx += (size_t)gridDim.x * CC_T)
    mask[idx] = 0ull;
  if (t == 0) blk_cnt = 0;
  for (int k = t; k < N; k += CC_T) {
    const float* o = sbox + (size_t)k * 12;
    scx[k] = o[8];
    scy[k] = o[9];
    sr[k] = o[10];
  }
  __syncthreads();
  int r0 = blockIdx.x, r1 = N - 1 - (int)blockIdx.x;
  for (int q = 0; q < 2; ++q) {
    int i = q ? r1 : r0;
    if (q && r1 == r0) break;
    float cxi = scx[i], cyi = scy[i], ri = sr[i];
    for (int j = i + 1 + t; j < N; j += CC_T) {
      float ddx = scx[j] - cxi, ddy = scy[j] - cyi;
      float rs = ri + sr[j];
      if (ddx * ddx + ddy * ddy <= rs * rs) {
        int idx = atomicAdd(&blk_cnt, 1);
        buf[idx] = ((unsigned)i << 16) | (unsigned)j;
      }
    }
  }
  __syncthreads();
  if (t == 0) blk_base = atomicAdd(count, blk_cnt);
  __syncthreads();
  for (int k = t; k < blk_cnt; k += CC_T)
    if (blk_base + k < cap) pairs[blk_base + k] = buf[k];
}

// K4: dense clip over survivors. First setter of each mask word appends
// (row,word) to the sparse worklist (atomicOr returns old value -> dedup).
__global__ void clip_kernel(const float* __restrict__ sbox,
                            const unsigned int* __restrict__ pairs,
                            const int* __restrict__ count,
                            unsigned long long* __restrict__ mask, int words,
                            int cap, unsigned int* __restrict__ wl,
                            int* __restrict__ wl_count) {
#pragma clang fp contract(off)
  int n = *count;
  if (n > cap) n = cap;
  for (int p = blockIdx.x * blockDim.x + threadIdx.x; p < n;
       p += gridDim.x * blockDim.x) {
    unsigned int pk = pairs[p];
    int i = pk >> 16, j = pk & 0xFFFF;
    const float* A = sbox + (size_t)i * 12;
    const float* B = sbox + (size_t)j * 12;
    float inter = clip_inter_area(A, B);
    float uni = A[11] + B[11] - inter;
    float iou = inter / fmaxf(uni, 1e-9f);
    if (iou > 0.7f) {
      unsigned long long old =
          atomicOr(&mask[(size_t)i * words + (j >> 6)], 1ull << (j & 63));
      if (old == 0ull) {
        int x = atomicAdd(wl_count, 1);
        if (x < WL_G_CAP) wl[x] = ((unsigned)i << 6) | (unsigned)(j >> 6);
      }
    }
  }
}

// Fallback direct path (large N / tiny workspace).
__global__ void iou_direct_kernel(const float* __restrict__ sbox,
                                  unsigned long long* __restrict__ mask, int N,
                                  int words) {
#pragma clang fp contract(off)
  int j = blockIdx.x * blockDim.x + threadIdx.x;
  int i = blockIdx.y;
  if (j >= N || j <= i) return;
  const float* A = sbox + (size_t)i * 12;
  const float* B = sbox + (size_t)j * 12;
  float ddx = B[8] - A[8], ddy = B[9] - A[9];
  float rs = A[10] + B[10];
  if (ddx * ddx + ddy * ddy > rs * rs) return;
  float inter = clip_inter_area(A, B);
  float uni = A[11] + B[11] - inter;
  float iou = inter / fmaxf(uni, 1e-9f);
  if (iou > 0.7f)
    atomicOr(&mask[(size_t)i * words + (j >> 6)], 1ull << (j & 63));
}

// K5: greedy sweep. Sparse path: counting-sort worklist by row, then one
// wave with register-resident sup (lane w owns word w) runs the serial
// chain barrier-free. Dense round-3 path as fallback.
__global__ void __launch_bounds__(1024) nms_sweep(
    const unsigned long long* __restrict__ mask, const int* __restrict__ order,
    const unsigned int* __restrict__ wl, const int* __restrict__ wl_count,
    int* __restrict__ out, int N, int words, int topn) {
  __shared__ unsigned long long sup_sh[64];
  __shared__ int prefix[65];
  __shared__ int h[2048], h2[2048];
  __shared__ unsigned int keys[WL_LDS_CAP];
  int t = threadIdx.x;
  int n_wl = *wl_count;  // uniform
  bool sparse = (words <= 32) && (N <= 2048) && (n_wl <= WL_LDS_CAP);

  if (sparse) {
    if (t < 64) sup_sh[t] = 0ull;
    for (int k = t; k < N; k += 1024) h[k] = 0;
    __syncthreads();
    for (int e = t; e < n_wl; e += 1024) atomicAdd(&h[wl[e] >> 6], 1);
    __syncthreads();
    // inclusive scan over rows (Hillis-Steele, ping-pong)
    int* src = h;
    int* dst = h2;
    for (int d = 1; d < N; d <<= 1) {
      for (int k = t; k < N; k += 1024)
        dst[k] = src[k] + (k >= d ? src[k - d] : 0);
      __syncthreads();
      int* tmp = src;
      src = dst;
      dst = tmp;
    }
    for (int k = t; k < N; k += 1024) dst[k] = k ? src[k - 1] : 0;
    __syncthreads();
    for (int e = t; e < n_wl; e += 1024) {
      unsigned key = wl[e];
      int pos = atomicAdd(&dst[key >> 6], 1);
      keys[pos] = key;
    }
    __syncthreads();
    if (t < 64) {
      int lane = t;
      unsigned long long sup = 0ull;
      unsigned long long supg = 0ull;
      int cur_g = -1;
      int chunks = (n_wl + 63) >> 6;
      for (int c = 0; c < chunks; ++c) {
        int idx = (c << 6) + lane;
        unsigned key = (idx < n_wl) ? keys[idx] : 0u;
        unsigned long long val = 0ull;
        if (idx < n_wl) {
          int rr = key >> 6, ww = key & 63;
          val = mask[(size_t)rr * words + ww];
        }
        int lim = n_wl - (c << 6);
        if (lim > 64) lim = 64;
        for (int e = 0; e < lim; ++e) {
          unsigned k2 = __shfl(key, e);
          unsigned long long v2 = __shfl(val, e);
          int r = k2 >> 6, w = k2 & 63, g = r >> 6;
          if (g != cur_g) {
            supg = __shfl(sup, g);
            cur_g = g;
          }
          bool kept = !((supg >> (r & 63)) & 1ull);
          if (kept) {
            if (lane == w) sup |= v2;
            if (w == g) supg |= v2;
          }
        }
      }
      sup_sh[lane] = (lane < words) ? sup : 0ull;
    }
    __syncthreads();
  } else {
    // dense fallback (round-3 algorithm)
    int lane = t & 63;
    int wave = t >> 6;
    if (t < 64) sup_sh[t] = 0ull;
    __syncthreads();
    int rstride = 1024 / words;
    int w2 = t % words;
    int rl0 = t / words;
    for (int g = 0; g < words; ++g) {
      if (wave == 0) {
        int r = g * 64 + lane;
        unsigned long long d = (r < N) ? mask[(size_t)r * words + g] : 0ull;
        unsigned long long supmask = sup_sh[g];
        for (int lp = 0; lp < 64; ++lp) {
          if (!((supmask >> lp) & 1ull)) supmask |= __shfl(d, lp);
        }
        if (lane == 0) sup_sh[g] = supmask;
      }
      __syncthreads();
      unsigned long long supg = sup_sh[g];
      if (w2 > g) {
        unsigned long long acc = 0ull;
        for (int rl = rl0; rl < 64; rl += rstride) {
          if (!((supg >> rl) & 1ull)) {
            int r = g * 64 + rl;
            if (r < N) acc |= mask[(size_t)r * words + w2];
          }
        }
        if (acc) atomicOr(&sup_sh[w2], acc);
      }
      __syncthreads();
    }
  }

  // output: per-word kept prefix, parallel scatter, -1 pad
  if (t == 0) {
    int acc = 0;
    for (int w = 0; w < words; ++w) {
      prefix[w] = acc;
      int hi = N - w * 64;
      unsigned long long keptw = ~sup_sh[w];
      if (hi < 64) keptw &= (1ull << hi) - 1ull;
      acc += __popcll(keptw);
    }
    prefix[words] = acc;
  }
  __syncthreads();
  int total = prefix[words];
  for (int i = t; i < N; i += 1024) {
    int w = i >> 6, b = i & 63;
    if (!((sup_sh[w] >> b) & 1ull)) {
      int pos = prefix[w] + __popcll(~sup_sh[w] & ((1ull << b) - 1ull));
      if (pos < topn) out[pos] = order[i];
    }
  }
  for (int k = total + t; k < topn; k += 1024) out[k] = -1;
}

extern "C" void kernel_launch(void* const* d_in, const int* in_sizes, int n_in,
                              void* d_out, int out_size, void* d_ws,
                              size_t ws_size, hipStream_t stream) {
  const float* boxes = (const float*)d_in[0];
  const float* scores = (const float*)d_in[1];
  int N = in_sizes[1];
  int words = (N + 63) / 64;
  int tiles = (N + RT - 1) / RT;

  char* ws = (char*)d_ws;
  size_t off = 0;
  unsigned long long* mask = (unsigned long long*)(ws + off);
  off += (size_t)N * words * sizeof(unsigned long long);
  float* sbox = (float*)(ws + off);
  off += (size_t)N * 12 * sizeof(float);
  int* order = (int*)(ws + off);
  off += (size_t)N * sizeof(int);
  int* count = (int*)(ws + off);
  int* wl_count = count + 1;
  off += 16;
  unsigned int* wl = (unsigned int*)(ws + off);
  off += (size_t)WL_G_CAP * sizeof(unsigned int);
  int* rank_part = (int*)(ws + off);
  off += (size_t)tiles * N * sizeof(int);
  unsigned int* pairs = (unsigned int*)(ws + off);
  size_t maxpairs = (size_t)N * (N - 1) / 2;
  bool compaction = (N <= 2048) && (off + maxpairs * 4 <= ws_size);
  int cap = compaction ? (int)maxpairs : 0;

  int* out = (int*)d_out;

  dim3 rgrid(tiles, tiles);
  rank_tiles<<<rgrid, RT, 0, stream>>>(scores, rank_part, count, wl_count, N);
  scatter_prep<<<tiles, RT, 0, stream>>>(boxes, rank_part, tiles, order, sbox,
                                         N);
  if (compaction) {
    circle_compact<<<(N + 1) / 2, CC_T, 0, stream>>>(sbox, mask, words, pairs,
                                                     count, N, cap);
    clip_kernel<<<256, 256, 0, stream>>>(sbox, pairs, count, mask, words, cap,
                                         wl, wl_count);
  } else {
    hipMemsetAsync(mask, 0, (size_t)N * words * 8, stream);
    dim3 grid((N + 255) / 256, N);
    iou_direct_kernel<<<grid, 256, 0, stream>>>(sbox, mask, N, words);
  }
  nms_sweep<<<1, 1024, 0, stream>>>(mask, order, wl, wl_count, out, N, words,
                                    out_size);
}

// Round 7
// 97.964 us; speedup vs baseline: 11.1533x; 1.0812x over previous
//
#include <hip/hip_runtime.h>

// Rotated NMS, N boxes [xc,yc,w,h,theta_deg], scores. Output: first 1000 kept
// original indices in score-sorted order, -1 padded. IoU math replicates the
// reference's float32 op order (contract off) — rounds 1-6: absmax 0.

#define WL_LDS_CAP 4096   // sparse-sweep worklist cap (falls back to dense)
#define WL_G_CAP 65536    // global worklist capacity
#define RT 256            // rank tile size

// K1: tiled rank. Block (bi,bj): threads = i-tile bi, LDS = j-tile bj.
__global__ void rank_tiles(const float* __restrict__ scores,
                           int* __restrict__ rank_part,
                           int* __restrict__ count,
                           int* __restrict__ wl_count, int N) {
  __shared__ float4 s4[RT / 4];
  if (blockIdx.x == 0 && blockIdx.y == 0 && threadIdx.x == 0) {
    *count = 0;
    *wl_count = 0;
  }
  int t = threadIdx.x;
  int jbase = blockIdx.y * RT;
  if (t < RT / 4) {
    int j0 = jbase + t * 4;
    float4 v;
    const float nanf_ = __int_as_float(0x7fc00000);  // pad: all cmps false
    v.x = (j0 + 0 < N) ? scores[j0 + 0] : nanf_;
    v.y = (j0 + 1 < N) ? scores[j0 + 1] : nanf_;
    v.z = (j0 + 2 < N) ? scores[j0 + 2] : nanf_;
    v.w = (j0 + 3 < N) ? scores[j0 + 3] : nanf_;
    s4[t] = v;
  }
  __syncthreads();
  int i = blockIdx.x * RT + t;
  if (i >= N) return;
  float si = scores[i];
  int r0 = 0, r1 = 0, r2 = 0, r3 = 0;
#pragma unroll 4
  for (int q = 0; q < RT / 4; ++q) {
    float4 v = s4[q];
    int jb = jbase + q * 4;
    r0 += (v.x > si) || (v.x == si && (jb + 0) < i);
    r1 += (v.y > si) || (v.y == si && (jb + 1) < i);
    r2 += (v.z > si) || (v.z == si && (jb + 2) < i);
    r3 += (v.w > si) || (v.w == si && (jb + 3) < i);
  }
  rank_part[(size_t)blockIdx.y * N + i] = r0 + r1 + r2 + r3;
}

// K2: sum partials -> rank r; scatter order[r]=i and prep sbox[r].
__global__ void scatter_prep(const float* __restrict__ boxes,
                             const int* __restrict__ rank_part, int tiles,
                             int* __restrict__ order, float* __restrict__ sbox,
                             int N) {
#pragma clang fp contract(off)
  int i = blockIdx.x * blockDim.x + threadIdx.x;
  if (i >= N) return;
  int r = 0;
  for (int b = 0; b < tiles; ++b) r += rank_part[(size_t)b * N + i];
  order[r] = i;
  float xc = boxes[i * 5 + 0], yc = boxes[i * 5 + 1];
  float w = boxes[i * 5 + 2], h = boxes[i * 5 + 3], th = boxes[i * 5 + 4];
  float ang = th * 0.017453292519943295f;
  float c = cosf(ang), sn = sinf(ang);
  float dx = w * 0.5f, dy = h * 0.5f;
  const float lx[4] = {-dx, dx, dx, -dx};
  const float ly[4] = {-dy, -dy, dy, dy};
  float* o = sbox + (size_t)r * 12;
  for (int k = 0; k < 4; ++k) {
    o[2 * k] = xc + lx[k] * c - ly[k] * sn;  // no FMA: match reference
    o[2 * k + 1] = yc + lx[k] * sn + ly[k] * c;
  }
  o[8] = xc;
  o[9] = yc;
  o[10] = 0.5f * sqrtf(w * w + h * h);
  o[11] = w * h;
}

// K3: circle+area prefilter. Block b owns rows {b, N-1-b}. Also zeroes the
// mask. Area test: IoU <= min/(A+B-min), so IoU>0.7 requires
// min_area > 0.7*max_area (0.699f = safety margin >> ulp error; conservative
// — the exact clip still decides survivors).
#define CC_T 256
__global__ void __launch_bounds__(CC_T) circle_compact(
    const float* __restrict__ sbox, unsigned long long* __restrict__ mask,
    int words, unsigned int* __restrict__ pairs, int* __restrict__ count,
    int N, int cap) {
  __shared__ float scx[2048], scy[2048], sr[2048], sa[2048];
  __shared__ unsigned int buf[2048];
  __shared__ int blk_cnt, blk_base;
  int t = threadIdx.x;
  size_t mtot = (size_t)N * words;
  for (size_t idx = (size_t)blockIdx.x * CC_T + t; idx < mtot;
       idx += (size_t)gridDim.x * CC_T)
    mask[idx] = 0ull;
  if (t == 0) blk_cnt = 0;
  for (int k = t; k < N; k += CC_T) {
    const float* o = sbox + (size_t)k * 12;
    scx[k] = o[8];
    scy[k] = o[9];
    sr[k] = o[10];
    sa[k] = o[11];
  }
  __syncthreads();
  int r0 = blockIdx.x, r1 = N - 1 - (int)blockIdx.x;
  for (int q = 0; q < 2; ++q) {
    int i = q ? r1 : r0;
    if (q && r1 == r0) break;
    float cxi = scx[i], cyi = scy[i], ri = sr[i], ai = sa[i];
    for (int j = i + 1 + t; j < N; j += CC_T) {
      float ddx = scx[j] - cxi, ddy = scy[j] - cyi;
      float rs = ri + sr[j];
      float aj = sa[j];
      float mn = fminf(ai, aj), mx = fmaxf(ai, aj);
      if (ddx * ddx + ddy * ddy <= rs * rs && mn > 0.699f * mx) {
        int idx = atomicAdd(&blk_cnt, 1);
        if (idx < 2048) buf[idx] = ((unsigned)i << 16) | (unsigned)j;
      }
    }
  }
  __syncthreads();
  int n = blk_cnt < 2048 ? blk_cnt : 2048;
  if (t == 0) blk_base = atomicAdd(count, n);
  __syncthreads();
  for (int k = t; k < n; k += CC_T)
    if (blk_base + k < cap) pairs[blk_base + k] = buf[k];
}

// K4: dense clip over survivors. Polygon lives in LDS (round-6: dynamic
// vertex indices forced scratch spills; LDS ping-pong buffers, lane-stride-1
// = conflict-free, no copy-back loop). First setter of each mask word
// appends (row,word) to the sparse worklist.
#define CL_T 256
__global__ void __launch_bounds__(CL_T) clip_kernel(
    const float* __restrict__ sbox, const unsigned int* __restrict__ pairs,
    const int* __restrict__ count, unsigned long long* __restrict__ mask,
    int words, int cap, unsigned int* __restrict__ wl,
    int* __restrict__ wl_count) {
#pragma clang fp contract(off)
  __shared__ float sc[2][2][8][CL_T];  // [buf][x/y][vert][tid] = 32 KB
  int t = threadIdx.x;
  int n = *count;
  if (n > cap) n = cap;
  for (int p = blockIdx.x * CL_T + t; p < n; p += gridDim.x * CL_T) {
    unsigned int pk = pairs[p];
    int i = pk >> 16, j = pk & 0xFFFF;
    const float* A = sbox + (size_t)i * 12;
    const float* B = sbox + (size_t)j * 12;
#pragma unroll
    for (int k = 0; k < 4; ++k) {
      sc[0][0][k][t] = A[2 * k];
      sc[0][1][k][t] = A[2 * k + 1];
    }
    int cnt = 4, cur = 0;
    for (int e = 0; e < 4; ++e) {
      float ax = B[2 * e], ay = B[2 * e + 1];
      int e2 = (e + 1) & 3;
      float bx = B[2 * e2], by = B[2 * e2 + 1];
      float ex = bx - ax, ey = by - ay;
      int nxtb = cur ^ 1;
      int ncnt = 0;
      for (int k = 0; k < cnt; ++k) {
        int kn = (k + 1 < cnt) ? k + 1 : 0;
        float px = sc[cur][0][k][t], py = sc[cur][1][k][t];
        float nx = sc[cur][0][kn][t], ny = sc[cur][1][kn][t];
        float dc = ex * (py - ay) - ey * (px - ax);
        float dn = ex * (ny - ay) - ey * (nx - ax);
        bool ic = (dc >= 0.0f), inx = (dn >= 0.0f);
        if (ic) {
          if (ncnt < 8) {
            sc[nxtb][0][ncnt][t] = px;
            sc[nxtb][1][ncnt][t] = py;
          }
          ++ncnt;
        }
        if (ic != inx) {
          float denom = dc - dn;
          float tp = (fabsf(denom) > 1e-12f) ? (dc / denom) : 0.0f;
          if (ncnt < 8) {
            sc[nxtb][0][ncnt][t] = px + tp * (nx - px);
            sc[nxtb][1][ncnt][t] = py + tp * (ny - py);
          }
          ++ncnt;
        }
      }
      cnt = ncnt > 8 ? 8 : ncnt;
      cur = nxtb;
    }
    float area = 0.0f;
    for (int k = 0; k < cnt; ++k) {
      int kn = (k + 1 < cnt) ? k + 1 : 0;
      area += sc[cur][0][k][t] * sc[cur][1][kn][t] -
              sc[cur][0][kn][t] * sc[cur][1][k][t];
    }
    float inter = fmaxf(0.5f * area, 0.0f);
    float uni = A[11] + B[11] - inter;
    float iou = inter / fmaxf(uni, 1e-9f);
    if (iou > 0.7f) {
      unsigned long long old =
          atomicOr(&mask[(size_t)i * words + (j >> 6)], 1ull << (j & 63));
      if (old == 0ull) {
        int x = atomicAdd(wl_count, 1);
        if (x < WL_G_CAP) wl[x] = ((unsigned)i << 6) | (unsigned)(j >> 6);
      }
    }
  }
}

// Fallback direct path (large N / tiny workspace) — register/scratch clip.
__device__ __forceinline__ float clip_inter_area_reg(
    const float* __restrict__ A, const float* __restrict__ B) {
#pragma clang fp contract(off)
  float Px[8], Py[8], Qx[8], Qy[8];
  for (int k = 0; k < 4; ++k) {
    Px[k] = A[2 * k];
    Py[k] = A[2 * k + 1];
  }
  int cnt = 4;
  for (int e = 0; e < 4; ++e) {
    float ax = B[2 * e], ay = B[2 * e + 1];
    int e2 = (e + 1) & 3;
    float bx = B[2 * e2], by = B[2 * e2 + 1];
    float ex = bx - ax, ey = by - ay;
    int ncnt = 0;
    for (int k = 0; k < cnt; ++k) {
      int kn = (k + 1 < cnt) ? k + 1 : 0;
      float dc = ex * (Py[k] - ay) - ey * (Px[k] - ax);
      float dn = ex * (Py[kn] - ay) - ey * (Px[kn] - ax);
      bool ic = (dc >= 0.0f), inx = (dn >= 0.0f);
      if (ic) {
        if (ncnt < 8) {
          Qx[ncnt] = Px[k];
          Qy[ncnt] = Py[k];
        }
        ++ncnt;
      }
      if (ic != inx) {
        float denom = dc - dn;
        float tp = (fabsf(denom) > 1e-12f) ? (dc / denom) : 0.0f;
        if (ncnt < 8) {
          Qx[ncnt] = Px[k] + tp * (Px[kn] - Px[k]);
          Qy[ncnt] = Py[k] + tp * (Py[kn] - Py[k]);
        }
        ++ncnt;
      }
    }
    cnt = ncnt > 8 ? 8 : ncnt;
    for (int k = 0; k < cnt; ++k) {
      Px[k] = Qx[k];
      Py[k] = Qy[k];
    }
  }
  float area = 0.0f;
  for (int k = 0; k < cnt; ++k) {
    int kn = (k + 1 < cnt) ? k + 1 : 0;
    area += Px[k] * Py[kn] - Px[kn] * Py[k];
  }
  return fmaxf(0.5f * area, 0.0f);
}

__global__ void iou_direct_kernel(const float* __restrict__ sbox,
                                  unsigned long long* __restrict__ mask, int N,
                                  int words) {
#pragma clang fp contract(off)
  int j = blockIdx.x * blockDim.x + threadIdx.x;
  int i = blockIdx.y;
  if (j >= N || j <= i) return;
  const float* A = sbox + (size_t)i * 12;
  const float* B = sbox + (size_t)j * 12;
  float ddx = B[8] - A[8], ddy = B[9] - A[9];
  float rs = A[10] + B[10];
  if (ddx * ddx + ddy * ddy > rs * rs) return;
  float mn = fminf(A[11], B[11]), mx = fmaxf(A[11], B[11]);
  if (!(mn > 0.699f * mx)) return;
  float inter = clip_inter_area_reg(A, B);
  float uni = A[11] + B[11] - inter;
  float iou = inter / fmaxf(uni, 1e-9f);
  if (iou > 0.7f)
    atomicOr(&mask[(size_t)i * words + (j >> 6)], 1ull << (j & 63));
}

// K5: greedy sweep. Sparse: counting-sort worklist by row (two-level shfl
// scan, 6 barriers — was 11-round Hillis-Steele), then one wave with
// register-resident sup runs the serial chain barrier-free.
__global__ void __launch_bounds__(1024) nms_sweep(
    const unsigned long long* __restrict__ mask, const int* __restrict__ order,
    const unsigned int* __restrict__ wl, const int* __restrict__ wl_count,
    int* __restrict__ out, int N, int words, int topn) {
  __shared__ unsigned long long sup_sh[64];
  __shared__ int prefix[65];
  __shared__ int h[2048], dst[2048];
  __shared__ int wtot[16];
  __shared__ unsigned int keys[WL_LDS_CAP];
  int t = threadIdx.x;
  int lane = t & 63;
  int wid = t >> 6;
  int n_wl = *wl_count;  // uniform
  bool sparse = (words <= 32) && (N <= 2048) && (n_wl <= WL_LDS_CAP);

  if (sparse) {
    if (t < 64) sup_sh[t] = 0ull;
    for (int k = t; k < N; k += 1024) h[k] = 0;
    __syncthreads();
    for (int e = t; e < n_wl; e += 1024) atomicAdd(&h[wl[e] >> 6], 1);
    __syncthreads();
    // two-level exclusive scan: thread t owns rows {2t, 2t+1}
    int a = (2 * t < N) ? h[2 * t] : 0;
    int b = (2 * t + 1 < N) ? h[2 * t + 1] : 0;
    int s = a + b;
    for (int d = 1; d < 64; d <<= 1) {
      int v = __shfl_up(s, d);
      if (lane >= d) s += v;
    }
    if (lane == 63) wtot[wid] = s;
    __syncthreads();
    if (wid == 0) {
      int w = (lane < 16) ? wtot[lane] : 0;
      for (int d = 1; d < 16; d <<= 1) {
        int v = __shfl_up(w, d);
        if (lane >= d) w += v;
      }
      if (lane < 16) wtot[lane] = w;  // inclusive wave totals
    }
    __syncthreads();
    int base = (wid ? wtot[wid - 1] : 0) + (s - (a + b));
    if (2 * t < N) dst[2 * t] = base;
    if (2 * t + 1 < N) dst[2 * t + 1] = base + a;
    __syncthreads();
    for (int e = t; e < n_wl; e += 1024) {
      unsigned key = wl[e];
      int pos = atomicAdd(&dst[key >> 6], 1);
      keys[pos] = key;
    }
    __syncthreads();
    if (t < 64) {
      unsigned long long sup = 0ull;
      unsigned long long supg = 0ull;
      int cur_g = -1;
      int chunks = (n_wl + 63) >> 6;
      for (int c = 0; c < chunks; ++c) {
        int idx = (c << 6) + lane;
        unsigned key = (idx < n_wl) ? keys[idx] : 0u;
        unsigned long long val = 0ull;
        if (idx < n_wl) {
          int rr = key >> 6, ww = key & 63;
          val = mask[(size_t)rr * words + ww];
        }
        int lim = n_wl - (c << 6);
        if (lim > 64) lim = 64;
        for (int e = 0; e < lim; ++e) {
          unsigned k2 = __shfl(key, e);
          unsigned long long v2 = __shfl(val, e);
          int r = k2 >> 6, w = k2 & 63, g = r >> 6;
          if (g != cur_g) {
            supg = __shfl(sup, g);
            cur_g = g;
          }
          bool kept = !((supg >> (r & 63)) & 1ull);
          if (kept) {
            if (lane == w) sup |= v2;
            if (w == g) supg |= v2;
          }
        }
      }
      sup_sh[lane] = (lane < words) ? sup : 0ull;
    }
    __syncthreads();
  } else {
    // dense fallback (round-3 algorithm)
    if (t < 64) sup_sh[t] = 0ull;
    __syncthreads();
    int rstride = 1024 / words;
    int w2 = t % words;
    int rl0 = t / words;
    for (int g = 0; g < words; ++g) {
      if (wid == 0) {
        int r = g * 64 + lane;
        unsigned long long d = (r < N) ? mask[(size_t)r * words + g] : 0ull;
        unsigned long long supmask = sup_sh[g];
        for (int lp = 0; lp < 64; ++lp) {
          if (!((supmask >> lp) & 1ull)) supmask |= __shfl(d, lp);
        }
        if (lane == 0) sup_sh[g] = supmask;
      }
      __syncthreads();
      unsigned long long supg = sup_sh[g];
      if (w2 > g) {
        unsigned long long acc = 0ull;
        for (int rl = rl0; rl < 64; rl += rstride) {
          if (!((supg >> rl) & 1ull)) {
            int r = g * 64 + rl;
            if (r < N) acc |= mask[(size_t)r * words + w2];
          }
        }
        if (acc) atomicOr(&sup_sh[w2], acc);
      }
      __syncthreads();
    }
  }

  // output: per-word kept prefix, parallel scatter, -1 pad
  if (t == 0) {
    int acc = 0;
    for (int w = 0; w < words; ++w) {
      prefix[w] = acc;
      int hi = N - w * 64;
      unsigned long long keptw = ~sup_sh[w];
      if (hi < 64) keptw &= (1ull << hi) - 1ull;
      acc += __popcll(keptw);
    }
    prefix[words] = acc;
  }
  __syncthreads();
  int total = prefix[words];
  for (int i = t; i < N; i += 1024) {
    int w = i >> 6, b = i & 63;
    if (!((sup_sh[w] >> b) & 1ull)) {
      int pos = prefix[w] + __popcll(~sup_sh[w] & ((1ull << b) - 1ull));
      if (pos < topn) out[pos] = order[i];
    }
  }
  for (int k = total + t; k < topn; k += 1024) out[k] = -1;
}

extern "C" void kernel_launch(void* const* d_in, const int* in_sizes, int n_in,
                              void* d_out, int out_size, void* d_ws,
                              size_t ws_size, hipStream_t stream) {
  const float* boxes = (const float*)d_in[0];
  const float* scores = (const float*)d_in[1];
  int N = in_sizes[1];
  int words = (N + 63) / 64;
  int tiles = (N + RT - 1) / RT;

  char* ws = (char*)d_ws;
  size_t off = 0;
  unsigned long long* mask = (unsigned long long*)(ws + off);
  off += (size_t)N * words * sizeof(unsigned long long);
  float* sbox = (float*)(ws + off);
  off += (size_t)N * 12 * sizeof(float);
  int* order = (int*)(ws + off);
  off += (size_t)N * sizeof(int);
  int* count = (int*)(ws + off);
  int* wl_count = count + 1;
  off += 16;
  unsigned int* wl = (unsigned int*)(ws + off);
  off += (size_t)WL_G_CAP * sizeof(unsigned int);
  int* rank_part = (int*)(ws + off);
  off += (size_t)tiles * N * sizeof(int);
  unsigned int* pairs = (unsigned int*)(ws + off);
  size_t maxpairs = (size_t)N * (N - 1) / 2;
  bool compaction = (N <= 2048) && (off + maxpairs * 4 <= ws_size);
  int cap = compaction ? (int)maxpairs : 0;

  int* out = (int*)d_out;

  dim3 rgrid(tiles, tiles);
  rank_tiles<<<rgrid, RT, 0, stream>>>(scores, rank_part, count, wl_count, N);
  scatter_prep<<<tiles, RT, 0, stream>>>(boxes, rank_part, tiles, order, sbox,
                                         N);
  if (compaction) {
    circle_compact<<<(N + 1) / 2, CC_T, 0, stream>>>(sbox, mask, words, pairs,
                                                     count, N, cap);
    clip_kernel<<<256, CL_T, 0, stream>>>(sbox, pairs, count, mask, words, cap,
                                          wl, wl_count);
  } else {
    hipMemsetAsync(mask, 0, (size_t)N * words * 8, stream);
    dim3 grid((N + 255) / 256, N);
    iou_direct_kernel<<<grid, 256, 0, stream>>>(sbox, mask, N, words);
  }
  nms_sweep<<<1, 1024, 0, stream>>>(mask, order, wl, wl_count, out, N, words,
                                    out_size);
}